// Round 4
// baseline (223.744 us; speedup 1.0000x reference)
//
#include <hip/hip_runtime.h>
#include <hip/hip_bf16.h>
#include <math.h>

// Round 4:
//  - GEMM: 64x64 block tiles (1536 blocks for QKV) to fix grid starvation
//    (was 384 blocks / 13% occupancy / 11% MfmaUtil).
//  - Attention: XOR-swizzled Ks (kills 8-way bank conflict on QK^T ds_read_b128),
//    epilogue writes split-bf16 directly (split1 kernel eliminated).

typedef __attribute__((ext_vector_type(8))) short bf16frag;  // 8 bf16 in 4 VGPRs
typedef __attribute__((ext_vector_type(4))) float f32x4;

__device__ inline unsigned short bf16_rne(float f) {
    unsigned int u = __float_as_uint(f);
    unsigned int r = u + 0x7fffu + ((u >> 16) & 1u);
    return (unsigned short)(r >> 16);
}

__device__ inline void split_val(float f, unsigned short& h, unsigned short& l) {
    h = bf16_rne(f);
    float hf = __uint_as_float(((unsigned int)h) << 16);
    float lf = f - hf;
    l = bf16_rne(lf);
}

// ---- fp32 -> (hi, lo) bf16 split: x + 4 weight matrices in one launch ----
__global__ __launch_bounds__(256) void split5(
    const float* __restrict__ x, const float* __restrict__ wq, const float* __restrict__ wk,
    const float* __restrict__ wv, const float* __restrict__ wo,
    unsigned short* xh, unsigned short* xl, unsigned short* qh, unsigned short* ql,
    unsigned short* kh, unsigned short* kl, unsigned short* vh, unsigned short* vl,
    unsigned short* oh, unsigned short* ol, int nx, int nw)
{
    const float* src; unsigned short *H, *L; int n;
    switch (blockIdx.z) {
        case 0: src = x;  H = xh; L = xl; n = nx; break;
        case 1: src = wq; H = qh; L = ql; n = nw; break;
        case 2: src = wk; H = kh; L = kl; n = nw; break;
        case 3: src = wv; H = vh; L = vl; n = nw; break;
        default: src = wo; H = oh; L = ol; n = nw; break;
    }
    int stride = gridDim.x * blockDim.x * 4;
    for (int i = (blockIdx.x * blockDim.x + threadIdx.x) * 4; i < n; i += stride) {
        float4 f = *(const float4*)(src + i);
        ushort4 h4, l4;
        split_val(f.x, h4.x, l4.x);
        split_val(f.y, h4.y, l4.y);
        split_val(f.z, h4.z, l4.z);
        split_val(f.w, h4.w, l4.w);
        *(ushort4*)(H + i) = h4;
        *(ushort4*)(L + i) = l4;
    }
}

// ---- split-bf16 MFMA GEMM: C[M x 512] = A[M x 512] @ W[512 x 512]^T ----
// Block: 256 thr = 4 waves (2x2), block tile 64x64, wave tile 32x32
// (2x2 frags of 16x16x32). K = 512. blockIdx.z selects (W, C) for fused QKV.
__global__ __launch_bounds__(256) void gemm_bf16s(
    const unsigned short* __restrict__ Ah, const unsigned short* __restrict__ Al,
    const unsigned short* __restrict__ W0h, const unsigned short* __restrict__ W0l,
    const unsigned short* __restrict__ W1h, const unsigned short* __restrict__ W1l,
    const unsigned short* __restrict__ W2h, const unsigned short* __restrict__ W2l,
    float* __restrict__ C0, float* __restrict__ C1, float* __restrict__ C2, int M)
{
    const unsigned short *Wh, *Wl; float* C;
    if (blockIdx.z == 0)      { Wh = W0h; Wl = W0l; C = C0; }
    else if (blockIdx.z == 1) { Wh = W1h; Wl = W1l; C = C1; }
    else                      { Wh = W2h; Wl = W2l; C = C2; }

    const int wid  = threadIdx.x >> 6;
    const int lane = threadIdx.x & 63;
    const int wr = wid >> 1, wc = wid & 1;
    const int m0 = blockIdx.y * 64 + wr * 32;
    const int n0 = blockIdx.x * 64 + wc * 32;
    const int lrow = lane & 15;
    const int lk   = (lane >> 4) << 3;   // k-offset 0,8,16,24

    const unsigned short* aH = Ah + (size_t)(m0 + lrow) * 512 + lk;
    const unsigned short* aL = Al + (size_t)(m0 + lrow) * 512 + lk;
    const unsigned short* bH = Wh + (size_t)(n0 + lrow) * 512 + lk;
    const unsigned short* bL = Wl + (size_t)(n0 + lrow) * 512 + lk;

    f32x4 acc[2][2];
    #pragma unroll
    for (int i = 0; i < 2; ++i)
        #pragma unroll
        for (int j = 0; j < 2; ++j)
            acc[i][j] = (f32x4){0.f, 0.f, 0.f, 0.f};

    #pragma unroll 2
    for (int k0 = 0; k0 < 512; k0 += 32) {
        bf16frag ah[2], al[2], bh[2], bl[2];
        #pragma unroll
        for (int mt = 0; mt < 2; ++mt) {
            ah[mt] = *(const bf16frag*)(aH + (size_t)mt * 16 * 512 + k0);
            al[mt] = *(const bf16frag*)(aL + (size_t)mt * 16 * 512 + k0);
            bh[mt] = *(const bf16frag*)(bH + (size_t)mt * 16 * 512 + k0);
            bl[mt] = *(const bf16frag*)(bL + (size_t)mt * 16 * 512 + k0);
        }
        #pragma unroll
        for (int mt = 0; mt < 2; ++mt)
            #pragma unroll
            for (int nt = 0; nt < 2; ++nt) {
                acc[mt][nt] = __builtin_amdgcn_mfma_f32_16x16x32_bf16(ah[mt], bh[nt], acc[mt][nt], 0, 0, 0);
                acc[mt][nt] = __builtin_amdgcn_mfma_f32_16x16x32_bf16(ah[mt], bl[nt], acc[mt][nt], 0, 0, 0);
                acc[mt][nt] = __builtin_amdgcn_mfma_f32_16x16x32_bf16(al[mt], bh[nt], acc[mt][nt], 0, 0, 0);
            }
    }

    // C/D layout (HW-verified): col = lane&15, row = (lane>>4)*4 + j
    const int rbase = (lane >> 4) * 4;
    #pragma unroll
    for (int mt = 0; mt < 2; ++mt)
        #pragma unroll
        for (int nt = 0; nt < 2; ++nt) {
            const int col = n0 + nt * 16 + lrow;
            #pragma unroll
            for (int j = 0; j < 4; ++j) {
                const int row = m0 + mt * 16 + rbase + j;
                C[(size_t)row * 512 + col] = acc[mt][nt][j];
            }
        }
}

// ---- windowed attention, LDS-staged K/V, swizzled Ks ----
// Block: head h, queries t0..t0+63. Stage K/V rows [t0-63, t0+63] (127 x 64 f32).
// Ks uses a 16B-block XOR swizzle (block j of row r stored at j^(r&15)) so the
// QK^T pattern (lane reads row qi+lane) spreads across all 8 bank groups.
// Epilogue writes split-bf16 (hi/lo) directly for the output projection.
__global__ __launch_bounds__(256) void swattn2(
    const float* __restrict__ Q, const float* __restrict__ K,
    const float* __restrict__ V,
    unsigned short* __restrict__ OH, unsigned short* __restrict__ OL, int T)
{
    __shared__ float Ks[127][64];
    __shared__ float Vs[127][64];
    __shared__ float ps[4][64];

    const int h  = blockIdx.x & 7;
    const int t0 = (blockIdx.x >> 3) * 64;
    const int kt0 = t0 - 63;
    const int tid = threadIdx.x;

    // coalesced staging: 16 threads per row, float4 each; Ks swizzled
    {
        const int r0 = tid >> 4;
        const int c  = (tid & 15) << 2;
        for (int r = r0; r < 127; r += 16) {
            const int kt = kt0 + r;
            float4 kv = {0.f, 0.f, 0.f, 0.f}, vv = {0.f, 0.f, 0.f, 0.f};
            if (kt >= 0) {
                kv = *(const float4*)(K + (size_t)kt * 512 + h * 64 + c);
                vv = *(const float4*)(V + (size_t)kt * 512 + h * 64 + c);
            }
            *(float4*)&Ks[r][c ^ ((r & 15) << 2)] = kv;
            *(float4*)&Vs[r][c] = vv;
        }
    }
    __syncthreads();

    const int wave = tid >> 6;
    const int lane = tid & 63;

    #pragma unroll 2
    for (int s = 0; s < 16; ++s) {
        const int qi = wave * 16 + s;
        const int t  = t0 + qi;
        const float* qrow = Q + (size_t)t * 512 + h * 64;

        // QK^T: lane = window position; swizzled Ks reads are conflict-free
        const int kt = t - 63 + lane;
        const int rr = qi + lane;
        const int rx = (rr & 15) << 2;
        const float* krow = &Ks[rr][0];
        float acc = 0.f;
        #pragma unroll
        for (int j = 0; j < 16; ++j) {
            float4 ka = *(const float4*)(krow + ((j << 2) ^ rx));
            float4 qa = *(const float4*)(qrow + (j << 2));
            acc = fmaf(qa.x, ka.x, acc);
            acc = fmaf(qa.y, ka.y, acc);
            acc = fmaf(qa.z, ka.z, acc);
            acc = fmaf(qa.w, ka.w, acc);
        }
        float sc = (kt >= 0) ? acc * 0.125f : -INFINITY;

        // wave softmax
        float m = sc;
        #pragma unroll
        for (int off = 32; off > 0; off >>= 1) m = fmaxf(m, __shfl_xor(m, off));
        float p = (kt >= 0) ? __expf(sc - m) : 0.f;
        float sum = p;
        #pragma unroll
        for (int off = 32; off > 0; off >>= 1) sum += __shfl_xor(sum, off);
        p /= sum;
        ps[wave][lane] = p;   // intra-wave LDS dep; compiler inserts lgkmcnt wait

        // PV: lane = head dim d; Vs reads are 2-way (free), ps broadcast
        float oacc = 0.f;
        #pragma unroll
        for (int w2 = 0; w2 < 64; w2 += 4) {
            float4 p4 = *(const float4*)&ps[wave][w2];
            oacc = fmaf(p4.x, Vs[qi + w2 + 0][lane], oacc);
            oacc = fmaf(p4.y, Vs[qi + w2 + 1][lane], oacc);
            oacc = fmaf(p4.z, Vs[qi + w2 + 2][lane], oacc);
            oacc = fmaf(p4.w, Vs[qi + w2 + 3][lane], oacc);
        }
        unsigned short hh, ll;
        split_val(oacc, hh, ll);
        const size_t oi = (size_t)t * 512 + h * 64 + lane;
        OH[oi] = hh;
        OL[oi] = ll;
    }
}

extern "C" void kernel_launch(void* const* d_in, const int* in_sizes, int n_in,
                              void* d_out, int out_size, void* d_ws, size_t ws_size,
                              hipStream_t stream) {
    const float* x  = (const float*)d_in[0];
    const float* Wq = (const float*)d_in[1];
    const float* Wk = (const float*)d_in[2];
    const float* Wv = (const float*)d_in[3];
    const float* Wo = (const float*)d_in[4];
    float* out = (float*)d_out;

    const int D = 512;
    const int T = in_sizes[0] / D;     // 4096
    const size_t tdf = (size_t)T * D;  // 2,097,152
    const size_t wsz = (size_t)D * D;  //   262,144

    float* Qb = (float*)d_ws;
    float* Kb = Qb + tdf;
    float* Vb = Kb + tdf;
    unsigned short* xh  = (unsigned short*)(Vb + tdf);
    unsigned short* xl  = xh + tdf;
    unsigned short* abh = xl + tdf;
    unsigned short* abl = abh + tdf;
    unsigned short* wqh = abl + tdf;
    unsigned short* wql = wqh + wsz;
    unsigned short* wkh = wql + wsz;
    unsigned short* wkl = wkh + wsz;
    unsigned short* wvh = wkl + wsz;
    unsigned short* wvl = wvh + wsz;
    unsigned short* woh = wvl + wsz;
    unsigned short* wol = woh + wsz;
    // ws use: 3*tdf*4 + 4*tdf*2 + 8*wsz*2 ≈ 46 MB

    dim3 blk(256);
    split5<<<dim3(256, 1, 5), blk, 0, stream>>>(
        x, Wq, Wk, Wv, Wo, xh, xl, wqh, wql, wkh, wkl, wvh, wvl, woh, wol,
        (int)tdf, (int)wsz);

    gemm_bf16s<<<dim3(D / 64, T / 64, 3), blk, 0, stream>>>(
        xh, xl, wqh, wql, wkh, wkl, wvh, wvl, Qb, Kb, Vb, T);

    swattn2<<<dim3(8 * T / 64), blk, 0, stream>>>(Qb, Kb, Vb, abh, abl, T);

    gemm_bf16s<<<dim3(D / 64, T / 64, 1), blk, 0, stream>>>(
        abh, abl, woh, wol, woh, wol, woh, wol, out, out, out, T);
}

// Round 6
// 216.130 us; speedup vs baseline: 1.0352x; 1.0352x over previous
//
#include <hip/hip_runtime.h>
#include <hip/hip_bf16.h>
#include <math.h>

// Round 6 (= round 5 resubmitted after acquisition timeout; Op aliased onto Qp
// to cut peak workspace 105 -> ~71 MB):
//  - GEMM: round-3 inner structure (128x128 block, wave 64x64, direct-global
//    frags) + split-K: QKV x2 (768 blocks), out-proj x4 (512 blocks).
//    Partials: QKV summed in swattn staging; out-proj summed by merge4.
//  - Attention: 32 queries/block (1024 blocks), swizzled Ks, split-bf16 epilogue.

typedef __attribute__((ext_vector_type(8))) short bf16frag;  // 8 bf16 in 4 VGPRs
typedef __attribute__((ext_vector_type(4))) float f32x4;

__device__ inline unsigned short bf16_rne(float f) {
    unsigned int u = __float_as_uint(f);
    unsigned int r = u + 0x7fffu + ((u >> 16) & 1u);
    return (unsigned short)(r >> 16);
}

__device__ inline void split_val(float f, unsigned short& h, unsigned short& l) {
    h = bf16_rne(f);
    float hf = __uint_as_float(((unsigned int)h) << 16);
    float lf = f - hf;
    l = bf16_rne(lf);
}

// ---- fp32 -> (hi, lo) bf16 split: x + 4 weight matrices in one launch ----
__global__ __launch_bounds__(256) void split5(
    const float* __restrict__ x, const float* __restrict__ wq, const float* __restrict__ wk,
    const float* __restrict__ wv, const float* __restrict__ wo,
    unsigned short* xh, unsigned short* xl, unsigned short* qh, unsigned short* ql,
    unsigned short* kh, unsigned short* kl, unsigned short* vh, unsigned short* vl,
    unsigned short* oh, unsigned short* ol, int nx, int nw)
{
    const float* src; unsigned short *H, *L; int n;
    switch (blockIdx.z) {
        case 0: src = x;  H = xh; L = xl; n = nx; break;
        case 1: src = wq; H = qh; L = ql; n = nw; break;
        case 2: src = wk; H = kh; L = kl; n = nw; break;
        case 3: src = wv; H = vh; L = vl; n = nw; break;
        default: src = wo; H = oh; L = ol; n = nw; break;
    }
    int stride = gridDim.x * blockDim.x * 4;
    for (int i = (blockIdx.x * blockDim.x + threadIdx.x) * 4; i < n; i += stride) {
        float4 f = *(const float4*)(src + i);
        ushort4 h4, l4;
        split_val(f.x, h4.x, l4.x);
        split_val(f.y, h4.y, l4.y);
        split_val(f.z, h4.z, l4.z);
        split_val(f.w, h4.w, l4.w);
        *(ushort4*)(H + i) = h4;
        *(ushort4*)(L + i) = l4;
    }
}

// ---- split-bf16 MFMA GEMM with split-K ----
// C_partial[kz] (M x 512) = A[:, kz-chunk] @ W[:, kz-chunk]^T  (3-term split-bf16)
// Block 128x128, 4 waves 2x2, wave tile 64x64 (4x4 frags of 16x16x32).
// blockIdx.z: mat = z % nmat (selects W/C), kz = z / nmat (K chunk).
__global__ __launch_bounds__(256) void gemm_bf16s(
    const unsigned short* __restrict__ Ah, const unsigned short* __restrict__ Al,
    const unsigned short* __restrict__ W0h, const unsigned short* __restrict__ W0l,
    const unsigned short* __restrict__ W1h, const unsigned short* __restrict__ W1l,
    const unsigned short* __restrict__ W2h, const unsigned short* __restrict__ W2l,
    float* __restrict__ C0, float* __restrict__ C1, float* __restrict__ C2,
    int M, int nmat, int kchunk)
{
    const int mat = blockIdx.z % nmat;
    const int kz  = blockIdx.z / nmat;
    const unsigned short *Wh, *Wl; float* C;
    if (mat == 0)      { Wh = W0h; Wl = W0l; C = C0; }
    else if (mat == 1) { Wh = W1h; Wl = W1l; C = C1; }
    else               { Wh = W2h; Wl = W2l; C = C2; }
    C += (size_t)kz * M * 512;            // partial buffer for this K chunk
    const int kstart = kz * kchunk;

    const int wid  = threadIdx.x >> 6;
    const int lane = threadIdx.x & 63;
    const int wr = wid >> 1, wc = wid & 1;
    const int m0 = blockIdx.y * 128 + wr * 64;
    const int n0 = blockIdx.x * 128 + wc * 64;
    const int lrow = lane & 15;
    const int lk   = (lane >> 4) << 3;    // k-offset 0,8,16,24

    const unsigned short* aH = Ah + (size_t)(m0 + lrow) * 512 + lk;
    const unsigned short* aL = Al + (size_t)(m0 + lrow) * 512 + lk;
    const unsigned short* bH = Wh + (size_t)(n0 + lrow) * 512 + lk;
    const unsigned short* bL = Wl + (size_t)(n0 + lrow) * 512 + lk;

    f32x4 acc[4][4];
    #pragma unroll
    for (int i = 0; i < 4; ++i)
        #pragma unroll
        for (int j = 0; j < 4; ++j)
            acc[i][j] = (f32x4){0.f, 0.f, 0.f, 0.f};

    #pragma unroll 2
    for (int k0 = kstart; k0 < kstart + kchunk; k0 += 32) {
        bf16frag ah[4], al[4], bh[4], bl[4];
        #pragma unroll
        for (int mt = 0; mt < 4; ++mt) {
            ah[mt] = *(const bf16frag*)(aH + (size_t)mt * 16 * 512 + k0);
            al[mt] = *(const bf16frag*)(aL + (size_t)mt * 16 * 512 + k0);
            bh[mt] = *(const bf16frag*)(bH + (size_t)mt * 16 * 512 + k0);
            bl[mt] = *(const bf16frag*)(bL + (size_t)mt * 16 * 512 + k0);
        }
        #pragma unroll
        for (int mt = 0; mt < 4; ++mt)
            #pragma unroll
            for (int nt = 0; nt < 4; ++nt) {
                acc[mt][nt] = __builtin_amdgcn_mfma_f32_16x16x32_bf16(ah[mt], bh[nt], acc[mt][nt], 0, 0, 0);
                acc[mt][nt] = __builtin_amdgcn_mfma_f32_16x16x32_bf16(ah[mt], bl[nt], acc[mt][nt], 0, 0, 0);
                acc[mt][nt] = __builtin_amdgcn_mfma_f32_16x16x32_bf16(al[mt], bh[nt], acc[mt][nt], 0, 0, 0);
            }
    }

    // C/D layout (HW-verified): col = lane&15, row = (lane>>4)*4 + j
    const int rbase = (lane >> 4) * 4;
    #pragma unroll
    for (int mt = 0; mt < 4; ++mt)
        #pragma unroll
        for (int nt = 0; nt < 4; ++nt) {
            const int col = n0 + nt * 16 + lrow;
            #pragma unroll
            for (int j = 0; j < 4; ++j) {
                const int row = m0 + mt * 16 + rbase + j;
                C[(size_t)row * 512 + col] = acc[mt][nt][j];
            }
        }
}

// ---- windowed attention, 32 queries/block, split-K partial sum on load ----
// Stage K/V rows [t0-63, t0+31] (95 x 64 f32), Ks XOR-swizzled (16B blocks).
// Epilogue writes split-bf16 (hi/lo) for the output projection.
__global__ __launch_bounds__(256) void swattn3(
    const float* __restrict__ Qp, const float* __restrict__ Kp,
    const float* __restrict__ Vp,
    unsigned short* __restrict__ OH, unsigned short* __restrict__ OL, int T)
{
    __shared__ float Ks[95][64];
    __shared__ float Vs[95][64];
    __shared__ float ps[4][64];

    const int h  = blockIdx.x & 7;
    const int t0 = (blockIdx.x >> 3) * 32;
    const int kt0 = t0 - 63;
    const int tid = threadIdx.x;
    const size_t tdf = (size_t)T * 512;

    // coalesced staging; sum the two split-K partials on load; Ks swizzled
    {
        const int r0 = tid >> 4;
        const int c  = (tid & 15) << 2;
        for (int r = r0; r < 95; r += 16) {
            const int kt = kt0 + r;
            float4 kv = {0.f, 0.f, 0.f, 0.f}, vv = {0.f, 0.f, 0.f, 0.f};
            if (kt >= 0) {
                const size_t off = (size_t)kt * 512 + h * 64 + c;
                float4 a = *(const float4*)(Kp + off);
                float4 b = *(const float4*)(Kp + off + tdf);
                kv = make_float4(a.x + b.x, a.y + b.y, a.z + b.z, a.w + b.w);
                a = *(const float4*)(Vp + off);
                b = *(const float4*)(Vp + off + tdf);
                vv = make_float4(a.x + b.x, a.y + b.y, a.z + b.z, a.w + b.w);
            }
            *(float4*)&Ks[r][c ^ ((r & 15) << 2)] = kv;
            *(float4*)&Vs[r][c] = vv;
        }
    }
    __syncthreads();

    const int wave = tid >> 6;
    const int lane = tid & 63;

    #pragma unroll 2
    for (int s = 0; s < 8; ++s) {
        const int qi = wave * 8 + s;         // 0..31
        const int t  = t0 + qi;
        const float* qrow0 = Qp + (size_t)t * 512 + h * 64;
        const float* qrow1 = qrow0 + tdf;

        // QK^T: lane = window position; swizzled Ks reads conflict-free
        const int kt = t - 63 + lane;
        const int rr = qi + lane;            // 0..94
        const int rx = (rr & 15) << 2;
        const float* krow = &Ks[rr][0];
        float acc = 0.f;
        #pragma unroll
        for (int j = 0; j < 16; ++j) {
            float4 ka = *(const float4*)(krow + ((j << 2) ^ rx));
            float4 q0 = *(const float4*)(qrow0 + (j << 2));
            float4 q1 = *(const float4*)(qrow1 + (j << 2));
            acc = fmaf(q0.x + q1.x, ka.x, acc);
            acc = fmaf(q0.y + q1.y, ka.y, acc);
            acc = fmaf(q0.z + q1.z, ka.z, acc);
            acc = fmaf(q0.w + q1.w, ka.w, acc);
        }
        float sc = (kt >= 0) ? acc * 0.125f : -INFINITY;

        // wave softmax
        float m = sc;
        #pragma unroll
        for (int off = 32; off > 0; off >>= 1) m = fmaxf(m, __shfl_xor(m, off));
        float p = (kt >= 0) ? __expf(sc - m) : 0.f;
        float sum = p;
        #pragma unroll
        for (int off = 32; off > 0; off >>= 1) sum += __shfl_xor(sum, off);
        p /= sum;
        ps[wave][lane] = p;

        // PV: lane = head dim d; Vs reads 2-way (free), ps broadcast
        float oacc = 0.f;
        #pragma unroll
        for (int w2 = 0; w2 < 64; w2 += 4) {
            float4 p4 = *(const float4*)&ps[wave][w2];
            oacc = fmaf(p4.x, Vs[qi + w2 + 0][lane], oacc);
            oacc = fmaf(p4.y, Vs[qi + w2 + 1][lane], oacc);
            oacc = fmaf(p4.z, Vs[qi + w2 + 2][lane], oacc);
            oacc = fmaf(p4.w, Vs[qi + w2 + 3][lane], oacc);
        }
        unsigned short hh, ll;
        split_val(oacc, hh, ll);
        const size_t oi = (size_t)t * 512 + h * 64 + lane;
        OH[oi] = hh;
        OL[oi] = ll;
    }
}

// ---- sum 4 split-K partials into the final output ----
__global__ __launch_bounds__(256) void merge4(
    const float* __restrict__ P, float* __restrict__ out, int n4)
{
    const int i = blockIdx.x * blockDim.x + threadIdx.x;
    if (i >= n4) return;
    const size_t n = (size_t)n4 * 4;
    float4 a = *(const float4*)(P + (size_t)i * 4);
    float4 b = *(const float4*)(P + (size_t)i * 4 + n);
    float4 c = *(const float4*)(P + (size_t)i * 4 + 2 * n);
    float4 d = *(const float4*)(P + (size_t)i * 4 + 3 * n);
    float4 o = make_float4(a.x + b.x + c.x + d.x, a.y + b.y + c.y + d.y,
                           a.z + b.z + c.z + d.z, a.w + b.w + c.w + d.w);
    *(float4*)(out + (size_t)i * 4) = o;
}

extern "C" void kernel_launch(void* const* d_in, const int* in_sizes, int n_in,
                              void* d_out, int out_size, void* d_ws, size_t ws_size,
                              hipStream_t stream) {
    const float* x  = (const float*)d_in[0];
    const float* Wq = (const float*)d_in[1];
    const float* Wk = (const float*)d_in[2];
    const float* Wv = (const float*)d_in[3];
    const float* Wo = (const float*)d_in[4];
    float* out = (float*)d_out;

    const int D = 512;
    const int T = in_sizes[0] / D;     // 4096
    const size_t tdf = (size_t)T * D;  // 2,097,152
    const size_t wsz = (size_t)D * D;  //   262,144

    float* Qp = (float*)d_ws;          // 2 partials each
    float* Kp = Qp + 2 * tdf;
    float* Vp = Kp + 2 * tdf;
    float* Op = Qp;                    // ALIAS: out-proj partials reuse Qp+Kp
                                       // (written only after swattn3 consumed them)
    unsigned short* xh  = (unsigned short*)(Vp + 2 * tdf);
    unsigned short* xl  = xh + tdf;
    unsigned short* abh = xl + tdf;
    unsigned short* abl = abh + tdf;
    unsigned short* wqh = abl + tdf;
    unsigned short* wql = wqh + wsz;
    unsigned short* wkh = wql + wsz;
    unsigned short* wkl = wkh + wsz;
    unsigned short* wvh = wkl + wsz;
    unsigned short* wvl = wvh + wsz;
    unsigned short* woh = wvl + wsz;
    unsigned short* wol = woh + wsz;
    // ws use: 6*tdf*4 + 4*tdf*2 + 8*wsz*2 ≈ 71 MB

    dim3 blk(256);
    split5<<<dim3(256, 1, 5), blk, 0, stream>>>(
        x, Wq, Wk, Wv, Wo, xh, xl, wqh, wql, wkh, wkl, wvh, wvl, woh, wol,
        (int)tdf, (int)wsz);

    // QKV: 128x128 tiles, split-K x2 -> 4*32*6 = 768 blocks
    gemm_bf16s<<<dim3(D / 128, T / 128, 6), blk, 0, stream>>>(
        xh, xl, wqh, wql, wkh, wkl, wvh, wvl, Qp, Kp, Vp, T, 3, 256);

    swattn3<<<dim3(8 * T / 32), blk, 0, stream>>>(Qp, Kp, Vp, abh, abl, T);

    // out-proj: split-K x4 -> 4*32*4 = 512 blocks (partials alias Qp/Kp space)
    gemm_bf16s<<<dim3(D / 128, T / 128, 4), blk, 0, stream>>>(
        abh, abl, woh, wol, woh, wol, woh, wol, Op, Op, Op, T, 1, 128);

    merge4<<<dim3((int)(tdf / 4 + 255) / 256), blk, 0, stream>>>(
        Op, out, (int)(tdf / 4));
}

// Round 7
// 162.137 us; speedup vs baseline: 1.3800x; 1.3330x over previous
//
#include <hip/hip_runtime.h>
#include <hip/hip_bf16.h>
#include <math.h>

// Round 7:
//  - GEMM: m97-style LDS-staged bf16 MFMA. Split-bf16 (3-term Markidis) folded
//    into ONE bf16 GEMM with K=1536 via K-region concat: [Ah|Ah|Al]@[Wh|Wl|Wh]^T.
//    global_load_lds (16B) staging with pre-swizzled global source; XOR-swizzled
//    ds_read_b128 fragment reads; 2-barrier K-loop. QKV: BM=128 (768 blocks);
//    out-proj: BM=64 (512 blocks, writes out directly).
//  - Attention: r6 structure WITHOUT split-K (32 q/block, swizzled Ks,
//    split-bf16 epilogue). merge4 eliminated.

typedef __attribute__((ext_vector_type(8))) short bf16frag;  // 8 bf16 = 16 B
typedef __attribute__((ext_vector_type(4))) float f32x4;

#if defined(__has_builtin)
#if __has_builtin(__builtin_amdgcn_global_load_lds)
#define HAVE_GLOAD_LDS 1
#endif
#endif

__device__ inline void gload16(const void* g, void* l, int lane) {
#ifdef HAVE_GLOAD_LDS
    // lane i of the wave lands at (uniform l) + i*16; g is per-lane.
    __builtin_amdgcn_global_load_lds(
        (const __attribute__((address_space(1))) void*)g,
        (__attribute__((address_space(3))) void*)l, 16, 0, 0);
#else
    *(bf16frag*)((char*)l + lane * 16) = *(const bf16frag*)g;
#endif
}

__device__ inline unsigned short bf16_rne(float f) {
    unsigned int u = __float_as_uint(f);
    unsigned int r = u + 0x7fffu + ((u >> 16) & 1u);
    return (unsigned short)(r >> 16);
}

__device__ inline void split_val(float f, unsigned short& h, unsigned short& l) {
    h = bf16_rne(f);
    float hf = __uint_as_float(((unsigned int)h) << 16);
    float lf = f - hf;
    l = bf16_rne(lf);
}

// ---- fp32 -> (hi, lo) bf16 split: x + 4 weight matrices in one launch ----
__global__ __launch_bounds__(256) void split5(
    const float* __restrict__ x, const float* __restrict__ wq, const float* __restrict__ wk,
    const float* __restrict__ wv, const float* __restrict__ wo,
    unsigned short* xh, unsigned short* xl, unsigned short* qh, unsigned short* ql,
    unsigned short* kh, unsigned short* kl, unsigned short* vh, unsigned short* vl,
    unsigned short* oh, unsigned short* ol, int nx, int nw)
{
    const float* src; unsigned short *H, *L; int n;
    switch (blockIdx.z) {
        case 0: src = x;  H = xh; L = xl; n = nx; break;
        case 1: src = wq; H = qh; L = ql; n = nw; break;
        case 2: src = wk; H = kh; L = kl; n = nw; break;
        case 3: src = wv; H = vh; L = vl; n = nw; break;
        default: src = wo; H = oh; L = ol; n = nw; break;
    }
    int stride = gridDim.x * blockDim.x * 4;
    for (int i = (blockIdx.x * blockDim.x + threadIdx.x) * 4; i < n; i += stride) {
        float4 f = *(const float4*)(src + i);
        ushort4 h4, l4;
        split_val(f.x, h4.x, l4.x);
        split_val(f.y, h4.y, l4.y);
        split_val(f.z, h4.z, l4.z);
        split_val(f.w, h4.w, l4.w);
        *(ushort4*)(H + i) = h4;
        *(ushort4*)(L + i) = l4;
    }
}

// ---- LDS-staged bf16 MFMA GEMM, K=1536 region-concat split-bf16 ----
// C[M x 512] = Ah@Wh^T + Ah@Wl^T + Al@Wh^T  (all [.][512] bf16 buffers)
// Block: 256 thr = 4 waves (2x2). Tile BM x 64, BK=64. Wave tile (BM/2) x 32.
// LDS: A tile [BM][64] + B tile [64][64] bf16, XOR-swizzled (kbyte ^= (r&7)<<4),
// filled linearly by global_load_lds from a pre-inverse-swizzled source address.
template<int BM>
__global__ __launch_bounds__(256) void gemm_lds(
    const unsigned short* __restrict__ Ah, const unsigned short* __restrict__ Al,
    const unsigned short* __restrict__ W0h, const unsigned short* __restrict__ W0l,
    const unsigned short* __restrict__ W1h, const unsigned short* __restrict__ W1l,
    const unsigned short* __restrict__ W2h, const unsigned short* __restrict__ W2l,
    float* __restrict__ C0, float* __restrict__ C1, float* __restrict__ C2)
{
    constexpr int MT     = BM / 32;            // m-frags per wave
    constexpr int HALF   = BM / 2;             // wave-tile rows
    constexpr int ABYTES = BM * 128;           // A-tile bytes (64 k * 2 B)
    constexpr int NINST  = (BM + 64) * 128 / 1024;  // 1KB staging insts
    constexpr int PER_WAVE = NINST / 4;

    __shared__ unsigned char lds[(BM + 64) * 128];

    const unsigned short *Wh, *Wl; float* C;
    if (blockIdx.z == 0)      { Wh = W0h; Wl = W0l; C = C0; }
    else if (blockIdx.z == 1) { Wh = W1h; Wl = W1l; C = C1; }
    else                      { Wh = W2h; Wl = W2l; C = C2; }

    const int tid  = threadIdx.x;
    const int wid  = tid >> 6;
    const int lane = tid & 63;
    const int wr = wid >> 1, wc = wid & 1;
    const int m0 = blockIdx.y * BM;
    const int n0 = blockIdx.x * 64;

    f32x4 acc[MT][2];
    #pragma unroll
    for (int i = 0; i < MT; ++i) {
        acc[i][0] = (f32x4){0.f, 0.f, 0.f, 0.f};
        acc[i][1] = (f32x4){0.f, 0.f, 0.f, 0.f};
    }

    // 24 K-steps of 64: region 0 = Ah.Wh, 1 = Ah.Wl, 2 = Al.Wh
    for (int ks = 0; ks < 24; ++ks) {
        const int rg = ks >> 3;
        const int k0 = (ks & 7) << 6;
        const unsigned short* As = (rg < 2) ? Ah : Al;
        const unsigned short* Bs = (rg == 1) ? Wl : Wh;

        __syncthreads();   // previous tile's frag reads complete
        #pragma unroll
        for (int j = 0; j < PER_WAVE; ++j) {
            const int o  = (wid * PER_WAVE + j) << 10;   // uniform per wave
            const int li = o + lane * 16;                // linear LDS byte
            const void* g;
            if (li < ABYTES) {            // uniform per inst (1KB | 16KB bdry)
                const int r  = li >> 7;
                const int kb = (li & 127) ^ ((r & 7) << 4);  // inverse swizzle
                g = As + (size_t)(m0 + r) * 512 + k0 + (kb >> 1);
            } else {
                const int lb = li - ABYTES;
                const int r  = lb >> 7;
                const int kb = (lb & 127) ^ ((r & 7) << 4);
                g = Bs + (size_t)(n0 + r) * 512 + k0 + (kb >> 1);
            }
            gload16(g, lds + o, lane);
        }
        __syncthreads();   // staging complete (compiler inserts vmcnt(0))

        #pragma unroll
        for (int ksub = 0; ksub < 2; ++ksub) {
            const int kbb = (ksub << 6) + ((lane >> 4) << 4);  // frag kbyte
            bf16frag af[MT], bf[2];
            #pragma unroll
            for (int mt = 0; mt < MT; ++mt) {
                const int r = wr * HALF + mt * 16 + (lane & 15);
                af[mt] = *(const bf16frag*)(lds + r * 128 + (kbb ^ ((r & 7) << 4)));
            }
            #pragma unroll
            for (int nt = 0; nt < 2; ++nt) {
                const int r = wc * 32 + nt * 16 + (lane & 15);
                bf[nt] = *(const bf16frag*)(lds + ABYTES + r * 128 + (kbb ^ ((r & 7) << 4)));
            }
            #pragma unroll
            for (int mt = 0; mt < MT; ++mt)
                #pragma unroll
                for (int nt = 0; nt < 2; ++nt)
                    acc[mt][nt] = __builtin_amdgcn_mfma_f32_16x16x32_bf16(
                        af[mt], bf[nt], acc[mt][nt], 0, 0, 0);
        }
    }

    // C/D layout (HW-verified): col = lane&15, row = (lane>>4)*4 + j
    const int rbase = (lane >> 4) * 4;
    #pragma unroll
    for (int mt = 0; mt < MT; ++mt)
        #pragma unroll
        for (int nt = 0; nt < 2; ++nt) {
            const int col = n0 + wc * 32 + nt * 16 + (lane & 15);
            #pragma unroll
            for (int j = 0; j < 4; ++j) {
                const int row = m0 + wr * HALF + mt * 16 + rbase + j;
                C[(size_t)row * 512 + col] = acc[mt][nt][j];
            }
        }
}

// ---- windowed attention, 32 queries/block, fp32 in, split-bf16 out ----
__global__ __launch_bounds__(256) void swattn4(
    const float* __restrict__ Q, const float* __restrict__ K,
    const float* __restrict__ V,
    unsigned short* __restrict__ OH, unsigned short* __restrict__ OL, int T)
{
    __shared__ float Ks[95][64];
    __shared__ float Vs[95][64];
    __shared__ float ps[4][64];

    const int h  = blockIdx.x & 7;
    const int t0 = (blockIdx.x >> 3) * 32;
    const int kt0 = t0 - 63;
    const int tid = threadIdx.x;

    // coalesced staging; Ks XOR-swizzled in 16B blocks
    {
        const int r0 = tid >> 4;
        const int c  = (tid & 15) << 2;
        for (int r = r0; r < 95; r += 16) {
            const int kt = kt0 + r;
            float4 kv = {0.f, 0.f, 0.f, 0.f}, vv = {0.f, 0.f, 0.f, 0.f};
            if (kt >= 0) {
                const size_t off = (size_t)kt * 512 + h * 64 + c;
                kv = *(const float4*)(K + off);
                vv = *(const float4*)(V + off);
            }
            *(float4*)&Ks[r][c ^ ((r & 15) << 2)] = kv;
            *(float4*)&Vs[r][c] = vv;
        }
    }
    __syncthreads();

    const int wave = tid >> 6;
    const int lane = tid & 63;

    #pragma unroll 2
    for (int s = 0; s < 8; ++s) {
        const int qi = wave * 8 + s;          // 0..31
        const int t  = t0 + qi;
        const float* qrow = Q + (size_t)t * 512 + h * 64;

        // QK^T: lane = window position; swizzled Ks reads conflict-free
        const int kt = t - 63 + lane;
        const int rr = qi + lane;             // 0..94
        const int rx = (rr & 15) << 2;
        const float* krow = &Ks[rr][0];
        float acc = 0.f;
        #pragma unroll
        for (int j = 0; j < 16; ++j) {
            float4 ka = *(const float4*)(krow + ((j << 2) ^ rx));
            float4 qa = *(const float4*)(qrow + (j << 2));
            acc = fmaf(qa.x, ka.x, acc);
            acc = fmaf(qa.y, ka.y, acc);
            acc = fmaf(qa.z, ka.z, acc);
            acc = fmaf(qa.w, ka.w, acc);
        }
        float sc = (kt >= 0) ? acc * 0.125f : -INFINITY;

        // wave softmax
        float m = sc;
        #pragma unroll
        for (int off = 32; off > 0; off >>= 1) m = fmaxf(m, __shfl_xor(m, off));
        float p = (kt >= 0) ? __expf(sc - m) : 0.f;
        float sum = p;
        #pragma unroll
        for (int off = 32; off > 0; off >>= 1) sum += __shfl_xor(sum, off);
        p /= sum;
        ps[wave][lane] = p;

        // PV: lane = head dim d; Vs reads 2-way (free), ps broadcast
        float oacc = 0.f;
        #pragma unroll
        for (int w2 = 0; w2 < 64; w2 += 4) {
            float4 p4 = *(const float4*)&ps[wave][w2];
            oacc = fmaf(p4.x, Vs[qi + w2 + 0][lane], oacc);
            oacc = fmaf(p4.y, Vs[qi + w2 + 1][lane], oacc);
            oacc = fmaf(p4.z, Vs[qi + w2 + 2][lane], oacc);
            oacc = fmaf(p4.w, Vs[qi + w2 + 3][lane], oacc);
        }
        unsigned short hh, ll;
        split_val(oacc, hh, ll);
        const size_t oi = (size_t)t * 512 + h * 64 + lane;
        OH[oi] = hh;
        OL[oi] = ll;
    }
}

extern "C" void kernel_launch(void* const* d_in, const int* in_sizes, int n_in,
                              void* d_out, int out_size, void* d_ws, size_t ws_size,
                              hipStream_t stream) {
    const float* x  = (const float*)d_in[0];
    const float* Wq = (const float*)d_in[1];
    const float* Wk = (const float*)d_in[2];
    const float* Wv = (const float*)d_in[3];
    const float* Wo = (const float*)d_in[4];
    float* out = (float*)d_out;

    const int D = 512;
    const int T = in_sizes[0] / D;     // 4096
    const size_t tdf = (size_t)T * D;  // 2,097,152
    const size_t wsz = (size_t)D * D;  //   262,144

    float* Qb = (float*)d_ws;
    float* Kb = Qb + tdf;
    float* Vb = Kb + tdf;
    unsigned short* xh  = (unsigned short*)(Vb + tdf);
    unsigned short* xl  = xh + tdf;
    unsigned short* abh = xl + tdf;
    unsigned short* abl = abh + tdf;
    unsigned short* wqh = abl + tdf;
    unsigned short* wql = wqh + wsz;
    unsigned short* wkh = wql + wsz;
    unsigned short* wkl = wkh + wsz;
    unsigned short* wvh = wkl + wsz;
    unsigned short* wvl = wvh + wsz;
    unsigned short* woh = wvl + wsz;
    unsigned short* wol = woh + wsz;
    // ws use: 3*tdf*4 + 4*tdf*2 + 8*wsz*2 = 24 + 16 + 4 = 44 MB

    dim3 blk(256);
    split5<<<dim3(256, 1, 5), blk, 0, stream>>>(
        x, Wq, Wk, Wv, Wo, xh, xl, wqh, wql, wkh, wkl, wvh, wvl, woh, wol,
        (int)tdf, (int)wsz);

    // QKV: BM=128 tiles -> (512/64) x (4096/128) x 3 = 768 blocks
    gemm_lds<128><<<dim3(D / 64, T / 128, 3), blk, 0, stream>>>(
        xh, xl, wqh, wql, wkh, wkl, wvh, wvl, Qb, Kb, Vb);

    swattn4<<<dim3(8 * T / 32), blk, 0, stream>>>(Qb, Kb, Vb, abh, abl, T);

    // out-proj: BM=64 tiles -> (512/64) x (4096/64) = 512 blocks
    gemm_lds<64><<<dim3(D / 64, T / 64, 1), blk, 0, stream>>>(
        abh, abl, woh, wol, woh, wol, woh, wol, out, out, out);
}

// Round 12
// 146.190 us; speedup vs baseline: 1.5305x; 1.1091x over previous
//
#include <hip/hip_runtime.h>
#include <hip/hip_bf16.h>
#include <math.h>

// Round 12 (= round 8 resubmitted; 4th attempt — all prior failures were
// infra-side: GPU acquisition/container. Kernel unchanged, audited twice):
//  - GEMM: m97-style core; epilogue templated: MODE 0 = fp32 C (out-proj),
//    MODE 1 = split-bf16 outputs, V written TRANSPOSED (Vt[n][63+t], 63-pad).
//  - Attention: full MFMA rewrite. Swapped QK^T (S^T via mfma(K,Q)) ->
//    near-lane-local softmax -> packed P(hi/lo) to LDS -> PV MFMA with
//    Vt B-operand. 3-term split-bf16 throughout. 32 q/block, 128 thr.

typedef __attribute__((ext_vector_type(8))) short bf16frag;   // 8 bf16 = 16 B
typedef __attribute__((ext_vector_type(4))) float f32x4;
typedef __attribute__((ext_vector_type(8))) unsigned short u16x8;

#if defined(__has_builtin)
#if __has_builtin(__builtin_amdgcn_global_load_lds)
#define HAVE_GLOAD_LDS 1
#endif
#endif

__device__ inline void gload16(const void* g, void* l, int lane) {
#ifdef HAVE_GLOAD_LDS
    __builtin_amdgcn_global_load_lds(
        (const __attribute__((address_space(1))) void*)g,
        (__attribute__((address_space(3))) void*)l, 16, 0, 0);
#else
    *(bf16frag*)((char*)l + lane * 16) = *(const bf16frag*)g;
#endif
}

__device__ inline unsigned short bf16_rne(float f) {
    unsigned int u = __float_as_uint(f);
    unsigned int r = u + 0x7fffu + ((u >> 16) & 1u);
    return (unsigned short)(r >> 16);
}

__device__ inline void split_val(float f, unsigned short& h, unsigned short& l) {
    h = bf16_rne(f);
    float hf = __uint_as_float(((unsigned int)h) << 16);
    float lf = f - hf;
    l = bf16_rne(lf);
}

// ---- fp32 -> (hi, lo) bf16 split: x + 4 weight matrices in one launch ----
__global__ __launch_bounds__(256) void split5(
    const float* __restrict__ x, const float* __restrict__ wq, const float* __restrict__ wk,
    const float* __restrict__ wv, const float* __restrict__ wo,
    unsigned short* xh, unsigned short* xl, unsigned short* qh, unsigned short* ql,
    unsigned short* kh, unsigned short* kl, unsigned short* vh, unsigned short* vl,
    unsigned short* oh, unsigned short* ol, int nx, int nw)
{
    const float* src; unsigned short *H, *L; int n;
    switch (blockIdx.z) {
        case 0: src = x;  H = xh; L = xl; n = nx; break;
        case 1: src = wq; H = qh; L = ql; n = nw; break;
        case 2: src = wk; H = kh; L = kl; n = nw; break;
        case 3: src = wv; H = vh; L = vl; n = nw; break;
        default: src = wo; H = oh; L = ol; n = nw; break;
    }
    int stride = gridDim.x * blockDim.x * 4;
    for (int i = (blockIdx.x * blockDim.x + threadIdx.x) * 4; i < n; i += stride) {
        float4 f = *(const float4*)(src + i);
        ushort4 h4, l4;
        split_val(f.x, h4.x, l4.x);
        split_val(f.y, h4.y, l4.y);
        split_val(f.z, h4.z, l4.z);
        split_val(f.w, h4.w, l4.w);
        *(ushort4*)(H + i) = h4;
        *(ushort4*)(L + i) = l4;
    }
}

// ---- zero the 63-column left pad of the transposed V buffers ----
__global__ __launch_bounds__(256) void zero_pad(
    unsigned short* __restrict__ VTH, unsigned short* __restrict__ VTL, int vtw)
{
    int i = blockIdx.x * blockDim.x + threadIdx.x;
    if (i < 512 * 63) {
        int r = i / 63, c = i % 63;
        VTH[(size_t)r * vtw + c] = 0;
        VTL[(size_t)r * vtw + c] = 0;
    }
}

// ---- LDS-staged bf16 MFMA GEMM, K=1536 region-concat split-bf16 ----
// MODE 0: C = fp32 [.][512] (out-proj -> d_out).
// MODE 1: split-bf16 out; z=0 -> (QHo,QLo) [T][512]; z=1 -> (KHo,KLo);
//         z=2 -> V transposed: VTHo[n][63+t] with row stride vtw.
template<int BM, int MODE>
__global__ __launch_bounds__(256) void gemm_lds(
    const unsigned short* __restrict__ Ah, const unsigned short* __restrict__ Al,
    const unsigned short* __restrict__ W0h, const unsigned short* __restrict__ W0l,
    const unsigned short* __restrict__ W1h, const unsigned short* __restrict__ W1l,
    const unsigned short* __restrict__ W2h, const unsigned short* __restrict__ W2l,
    float* __restrict__ C0, float* __restrict__ C1, float* __restrict__ C2,
    unsigned short* __restrict__ QHo, unsigned short* __restrict__ QLo,
    unsigned short* __restrict__ KHo, unsigned short* __restrict__ KLo,
    unsigned short* __restrict__ VTHo, unsigned short* __restrict__ VTLo, int vtw)
{
    constexpr int MT     = BM / 32;
    constexpr int HALF   = BM / 2;
    constexpr int ABYTES = BM * 128;
    constexpr int NINST  = (BM + 64) * 128 / 1024;
    constexpr int PER_WAVE = NINST / 4;

    __shared__ unsigned char lds[(BM + 64) * 128];

    const unsigned short *Wh, *Wl;
    if (blockIdx.z == 0)      { Wh = W0h; Wl = W0l; }
    else if (blockIdx.z == 1) { Wh = W1h; Wl = W1l; }
    else                      { Wh = W2h; Wl = W2l; }

    const int tid  = threadIdx.x;
    const int wid  = tid >> 6;
    const int lane = tid & 63;
    const int wr = wid >> 1, wc = wid & 1;
    const int m0 = blockIdx.y * BM;
    const int n0 = blockIdx.x * 64;

    f32x4 acc[MT][2];
    #pragma unroll
    for (int i = 0; i < MT; ++i) {
        acc[i][0] = (f32x4){0.f, 0.f, 0.f, 0.f};
        acc[i][1] = (f32x4){0.f, 0.f, 0.f, 0.f};
    }

    for (int ks = 0; ks < 24; ++ks) {
        const int rg = ks >> 3;
        const int k0 = (ks & 7) << 6;
        const unsigned short* As = (rg < 2) ? Ah : Al;
        const unsigned short* Bs = (rg == 1) ? Wl : Wh;

        __syncthreads();
        #pragma unroll
        for (int j = 0; j < PER_WAVE; ++j) {
            const int o  = (wid * PER_WAVE + j) << 10;
            const int li = o + lane * 16;
            const void* g;
            if (li < ABYTES) {
                const int r  = li >> 7;
                const int kb = (li & 127) ^ ((r & 7) << 4);
                g = As + (size_t)(m0 + r) * 512 + k0 + (kb >> 1);
            } else {
                const int lb = li - ABYTES;
                const int r  = lb >> 7;
                const int kb = (lb & 127) ^ ((r & 7) << 4);
                g = Bs + (size_t)(n0 + r) * 512 + k0 + (kb >> 1);
            }
            gload16(g, lds + o, lane);
        }
        __syncthreads();

        #pragma unroll
        for (int ksub = 0; ksub < 2; ++ksub) {
            const int kbb = (ksub << 6) + ((lane >> 4) << 4);
            bf16frag af[MT], bf[2];
            #pragma unroll
            for (int mt = 0; mt < MT; ++mt) {
                const int r = wr * HALF + mt * 16 + (lane & 15);
                af[mt] = *(const bf16frag*)(lds + r * 128 + (kbb ^ ((r & 7) << 4)));
            }
            #pragma unroll
            for (int nt = 0; nt < 2; ++nt) {
                const int r = wc * 32 + nt * 16 + (lane & 15);
                bf[nt] = *(const bf16frag*)(lds + ABYTES + r * 128 + (kbb ^ ((r & 7) << 4)));
            }
            #pragma unroll
            for (int mt = 0; mt < MT; ++mt)
                #pragma unroll
                for (int nt = 0; nt < 2; ++nt)
                    acc[mt][nt] = __builtin_amdgcn_mfma_f32_16x16x32_bf16(
                        af[mt], bf[nt], acc[mt][nt], 0, 0, 0);
        }
    }

    // C/D layout (HW-verified): col = lane&15, row = (lane>>4)*4 + j
    const int rbase = (lane >> 4) * 4;
    #pragma unroll
    for (int mt = 0; mt < MT; ++mt)
        #pragma unroll
        for (int nt = 0; nt < 2; ++nt) {
            const int col = n0 + wc * 32 + nt * 16 + (lane & 15);
            #pragma unroll
            for (int j = 0; j < 4; ++j) {
                const int row = m0 + wr * HALF + mt * 16 + rbase + j;
                if constexpr (MODE == 0) {
                    float* C = (blockIdx.z == 0) ? C0 : (blockIdx.z == 1 ? C1 : C2);
                    C[(size_t)row * 512 + col] = acc[mt][nt][j];
                } else {
                    unsigned short hh, ll;
                    split_val(acc[mt][nt][j], hh, ll);
                    if (blockIdx.z == 0) {
                        QHo[(size_t)row * 512 + col] = hh;
                        QLo[(size_t)row * 512 + col] = ll;
                    } else if (blockIdx.z == 1) {
                        KHo[(size_t)row * 512 + col] = hh;
                        KLo[(size_t)row * 512 + col] = ll;
                    } else {
                        VTHo[(size_t)col * vtw + 63 + row] = hh;
                        VTLo[(size_t)col * vtw + 63 + row] = ll;
                    }
                }
            }
        }
}

// ---- MFMA windowed attention: 32 queries/block, 128 thr (2 waves) ----
// Wave qt owns queries qt*16..qt*16+15. Window rows w in [0,95): kt = t0-63+w.
// S^T = mfma(K, Q): lane holds col q = qt*16+(lane&15), rows w. Softmax is
// lane-local over 24 regs + 2 shfl_xor. P split-bf16 packed to LDS; PV MFMA
// with A = P rows q (k=w), B = Vt rows d (k=w). Split-bf16 epilogue.
__global__ __launch_bounds__(128) void swattn5(
    const unsigned short* __restrict__ QH, const unsigned short* __restrict__ QL,
    const unsigned short* __restrict__ KH, const unsigned short* __restrict__ KL,
    const unsigned short* __restrict__ VTH, const unsigned short* __restrict__ VTL,
    unsigned short* __restrict__ OH, unsigned short* __restrict__ OL, int T)
{
    __shared__ unsigned short KsH[96 * 88], KsL[96 * 88];    // rows w, pad 88
    __shared__ unsigned short VtH[64 * 104], VtL[64 * 104];  // rows d, pad 104
    __shared__ unsigned short PsH[32 * 104], PsL[32 * 104];  // rows q, pad 104

    const int h   = blockIdx.x & 7;
    const int t0  = (blockIdx.x >> 3) * 32;
    const int kt0 = t0 - 63;
    const int tid = threadIdx.x;
    const int vtw = T + 64;

    // stage K window rows (zero rows for kt<0 and the w=95 pad row)
    {
        const int c = tid & 7;
        for (int r = tid >> 3; r < 96; r += 16) {
            const int kt = kt0 + r;
            u16x8 kh = {0,0,0,0,0,0,0,0}, kl = {0,0,0,0,0,0,0,0};
            if (kt >= 0 && r < 95) {
                const size_t off = (size_t)kt * 512 + h * 64 + c * 8;
                kh = *(const u16x8*)(KH + off);
                kl = *(const u16x8*)(KL + off);
            }
            *(u16x8*)&KsH[r * 88 + c * 8] = kh;
            *(u16x8*)&KsL[r * 88 + c * 8] = kl;
        }
    }
    // stage Vt rows: cols w=0..95 read from global col t0+w (63-pad covers kt<0)
    for (int i = tid; i < 64 * 12; i += 128) {
        const int d = i / 12, c = i % 12;
        const size_t off = (size_t)(h * 64 + d) * vtw + t0 + c * 8;
        *(u16x8*)&VtH[d * 104 + c * 8] = *(const u16x8*)(VTH + off);
        *(u16x8*)&VtL[d * 104 + c * 8] = *(const u16x8*)(VTL + off);
    }
    __syncthreads();

    const int wid  = tid >> 6;      // qt
    const int lane = tid & 63;
    const int lr = lane & 15;
    const int lg = lane >> 4;

    // Q B-frags direct from global (validated pattern: row=lane&15, k=(lane>>4)*8)
    bf16frag qfh[2], qfl[2];
    {
        const size_t base = (size_t)(t0 + wid * 16 + lr) * 512 + h * 64 + lg * 8;
        qfh[0] = *(const bf16frag*)(QH + base);
        qfh[1] = *(const bf16frag*)(QH + base + 32);
        qfl[0] = *(const bf16frag*)(QL + base);
        qfl[1] = *(const bf16frag*)(QL + base + 32);
    }

    // S^T = K @ Q^T, 3-term split
    f32x4 s[6];
    #pragma unroll
    for (int wt = 0; wt < 6; ++wt) s[wt] = (f32x4){0.f, 0.f, 0.f, 0.f};
    #pragma unroll
    for (int ksub = 0; ksub < 2; ++ksub) {
        #pragma unroll
        for (int wt = 0; wt < 6; ++wt) {
            const int a = (wt * 16 + lr) * 88 + lg * 8 + ksub * 32;
            bf16frag akh = *(const bf16frag*)&KsH[a];
            bf16frag akl = *(const bf16frag*)&KsL[a];
            s[wt] = __builtin_amdgcn_mfma_f32_16x16x32_bf16(akh, qfh[ksub], s[wt], 0, 0, 0);
            s[wt] = __builtin_amdgcn_mfma_f32_16x16x32_bf16(akh, qfl[ksub], s[wt], 0, 0, 0);
            s[wt] = __builtin_amdgcn_mfma_f32_16x16x32_bf16(akl, qfh[ksub], s[wt], 0, 0, 0);
        }
    }

    // scale + band mask + softmax (w-reduction: 24 lane-local + shfl 16,32)
    const int q_local = wid * 16 + lr;
    float sc[6][4];
    float mx = -3e38f;
    #pragma unroll
    for (int wt = 0; wt < 6; ++wt)
        #pragma unroll
        for (int j = 0; j < 4; ++j) {
            const int w = wt * 16 + lg * 4 + j;
            const bool valid = (w >= q_local) && (w <= q_local + 63) && (kt0 + w >= 0);
            sc[wt][j] = valid ? s[wt][j] * 0.125f : -3e38f;
            mx = fmaxf(mx, sc[wt][j]);
        }
    mx = fmaxf(mx, __shfl_xor(mx, 16));
    mx = fmaxf(mx, __shfl_xor(mx, 32));
    float sum = 0.f;
    #pragma unroll
    for (int wt = 0; wt < 6; ++wt)
        #pragma unroll
        for (int j = 0; j < 4; ++j) {
            sc[wt][j] = __expf(sc[wt][j] - mx);
            sum += sc[wt][j];
        }
    sum += __shfl_xor(sum, 16);
    sum += __shfl_xor(sum, 32);
    const float inv = 1.f / sum;

    // P -> split bf16, packed ushort4 writes into own q-row
    #pragma unroll
    for (int wt = 0; wt < 6; ++wt) {
        ushort4 ph, pl;
        unsigned short hh, ll;
        split_val(sc[wt][0] * inv, hh, ll); ph.x = hh; pl.x = ll;
        split_val(sc[wt][1] * inv, hh, ll); ph.y = hh; pl.y = ll;
        split_val(sc[wt][2] * inv, hh, ll); ph.z = hh; pl.z = ll;
        split_val(sc[wt][3] * inv, hh, ll); ph.w = hh; pl.w = ll;
        const int col = wt * 16 + lg * 4;
        *(ushort4*)&PsH[q_local * 104 + col] = ph;
        *(ushort4*)&PsL[q_local * 104 + col] = pl;
    }
    // no __syncthreads needed: each wave reads only its own P rows (intra-wave dep)

    // PV: out[q][d] = sum_w P[q][w] * Vt[d][w], 3-term split, k = 96
    f32x4 oa[4];
    #pragma unroll
    for (int dt = 0; dt < 4; ++dt) oa[dt] = (f32x4){0.f, 0.f, 0.f, 0.f};
    #pragma unroll
    for (int ks = 0; ks < 3; ++ks) {
        const int ka = lg * 8 + ks * 32;
        bf16frag pah = *(const bf16frag*)&PsH[(wid * 16 + lr) * 104 + ka];
        bf16frag pal = *(const bf16frag*)&PsL[(wid * 16 + lr) * 104 + ka];
        #pragma unroll
        for (int dt = 0; dt < 4; ++dt) {
            const int a = (dt * 16 + lr) * 104 + ka;
            bf16frag bvh = *(const bf16frag*)&VtH[a];
            bf16frag bvl = *(const bf16frag*)&VtL[a];
            oa[dt] = __builtin_amdgcn_mfma_f32_16x16x32_bf16(pah, bvh, oa[dt], 0, 0, 0);
            oa[dt] = __builtin_amdgcn_mfma_f32_16x16x32_bf16(pal, bvh, oa[dt], 0, 0, 0);
            oa[dt] = __builtin_amdgcn_mfma_f32_16x16x32_bf16(pah, bvl, oa[dt], 0, 0, 0);
        }
    }

    // epilogue: C-frag col = d, rows q; write split-bf16 for out-proj
    #pragma unroll
    for (int dt = 0; dt < 4; ++dt) {
        const int d = dt * 16 + lr;
        #pragma unroll
        for (int j = 0; j < 4; ++j) {
            const int t = t0 + wid * 16 + lg * 4 + j;
            unsigned short hh, ll;
            split_val(oa[dt][j], hh, ll);
            const size_t oi = (size_t)t * 512 + h * 64 + d;
            OH[oi] = hh;
            OL[oi] = ll;
        }
    }
}

extern "C" void kernel_launch(void* const* d_in, const int* in_sizes, int n_in,
                              void* d_out, int out_size, void* d_ws, size_t ws_size,
                              hipStream_t stream) {
    const float* x  = (const float*)d_in[0];
    const float* Wq = (const float*)d_in[1];
    const float* Wk = (const float*)d_in[2];
    const float* Wv = (const float*)d_in[3];
    const float* Wo = (const float*)d_in[4];
    float* out = (float*)d_out;

    const int D = 512;
    const int T = in_sizes[0] / D;        // 4096
    const size_t tdf = (size_t)T * D;     // 2,097,152
    const size_t wsz = (size_t)D * D;     //   262,144
    const int vtw = T + 64;
    const size_t vts = (size_t)D * vtw;   // 2,129,920

    unsigned short* qh  = (unsigned short*)d_ws;
    unsigned short* ql  = qh + tdf;
    unsigned short* kh  = ql + tdf;
    unsigned short* kl  = kh + tdf;
    unsigned short* vth = kl + tdf;
    unsigned short* vtl = vth + vts;
    unsigned short* abh = vtl + vts;
    unsigned short* abl = abh + tdf;
    unsigned short* xh  = abl + tdf;
    unsigned short* xl  = xh + tdf;
    unsigned short* wqh = xl + tdf;
    unsigned short* wql = wqh + wsz;
    unsigned short* wkh = wql + wsz;
    unsigned short* wkl = wkh + wsz;
    unsigned short* wvh = wkl + wsz;
    unsigned short* wvl = wvh + wsz;
    unsigned short* woh = wvl + wsz;
    unsigned short* wol = woh + wsz;
    // ws use: (8*tdf + 2*vts + 8*wsz) * 2B ≈ 46 MB

    dim3 blk(256);
    split5<<<dim3(256, 1, 5), blk, 0, stream>>>(
        x, Wq, Wk, Wv, Wo, xh, xl, wqh, wql, wkh, wkl, wvh, wvl, woh, wol,
        (int)tdf, (int)wsz);

    zero_pad<<<dim3((512 * 63 + 255) / 256), blk, 0, stream>>>(vth, vtl, vtw);

    // QKV: split-bf16 outputs; V transposed. 8 x 32 x 3 = 768 blocks
    gemm_lds<128, 1><<<dim3(D / 64, T / 128, 3), blk, 0, stream>>>(
        xh, xl, wqh, wql, wkh, wkl, wvh, wvl,
        nullptr, nullptr, nullptr,
        qh, ql, kh, kl, vth, vtl, vtw);

    // attention: 8 heads x T/32 = 1024 blocks x 128 thr
    swattn5<<<dim3(8 * T / 32), dim3(128), 0, stream>>>(
        qh, ql, kh, kl, vth, vtl, abh, abl, T);

    // out-proj: fp32 to d_out. 8 x 64 = 512 blocks
    gemm_lds<64, 0><<<dim3(D / 64, T / 64, 1), blk, 0, stream>>>(
        abh, abl, woh, wol, woh, wol, woh, wol,
        out, out, out,
        nullptr, nullptr, nullptr, nullptr, nullptr, nullptr, 0);
}

// Round 13
// 140.354 us; speedup vs baseline: 1.5941x; 1.0416x over previous
//
#include <hip/hip_runtime.h>
#include <hip/hip_bf16.h>
#include <math.h>

// Round 13:
//  - GEMMs: double-buffered K-loop (stage next tile BEFORE computing current,
//    ONE barrier/step) -> staging latency hides under MFMA+ds_read.
//  - V^T computed natively as Wv @ x^T (swapped operands) -> coalesced C-write
//    along t; kills the 2B-scatter write amplification of round 12.
//  - Q/K/V^T fused in one 768-block launch (linear block-id decode).
//  - swattn5 (MFMA attention): byte-identical to round 12 (validated).

typedef __attribute__((ext_vector_type(8))) short bf16frag;   // 8 bf16 = 16 B
typedef __attribute__((ext_vector_type(4))) float f32x4;
typedef __attribute__((ext_vector_type(8))) unsigned short u16x8;

#if defined(__has_builtin)
#if __has_builtin(__builtin_amdgcn_global_load_lds)
#define HAVE_GLOAD_LDS 1
#endif
#endif

__device__ inline void gload16(const void* g, void* l, int lane) {
#ifdef HAVE_GLOAD_LDS
    __builtin_amdgcn_global_load_lds(
        (const __attribute__((address_space(1))) void*)g,
        (__attribute__((address_space(3))) void*)l, 16, 0, 0);
#else
    *(bf16frag*)((char*)l + lane * 16) = *(const bf16frag*)g;
#endif
}

__device__ inline unsigned short bf16_rne(float f) {
    unsigned int u = __float_as_uint(f);
    unsigned int r = u + 0x7fffu + ((u >> 16) & 1u);
    return (unsigned short)(r >> 16);
}

__device__ inline void split_val(float f, unsigned short& h, unsigned short& l) {
    h = bf16_rne(f);
    float hf = __uint_as_float(((unsigned int)h) << 16);
    float lf = f - hf;
    l = bf16_rne(lf);
}

// ---- fp32 -> (hi, lo) bf16 split: x + 4 weight matrices in one launch ----
__global__ __launch_bounds__(256) void split5(
    const float* __restrict__ x, const float* __restrict__ wq, const float* __restrict__ wk,
    const float* __restrict__ wv, const float* __restrict__ wo,
    unsigned short* xh, unsigned short* xl, unsigned short* qh, unsigned short* ql,
    unsigned short* kh, unsigned short* kl, unsigned short* vh, unsigned short* vl,
    unsigned short* oh, unsigned short* ol, int nx, int nw)
{
    const float* src; unsigned short *H, *L; int n;
    switch (blockIdx.z) {
        case 0: src = x;  H = xh; L = xl; n = nx; break;
        case 1: src = wq; H = qh; L = ql; n = nw; break;
        case 2: src = wk; H = kh; L = kl; n = nw; break;
        case 3: src = wv; H = vh; L = vl; n = nw; break;
        default: src = wo; H = oh; L = ol; n = nw; break;
    }
    int stride = gridDim.x * blockDim.x * 4;
    for (int i = (blockIdx.x * blockDim.x + threadIdx.x) * 4; i < n; i += stride) {
        float4 f = *(const float4*)(src + i);
        ushort4 h4, l4;
        split_val(f.x, h4.x, l4.x);
        split_val(f.y, h4.y, l4.y);
        split_val(f.z, h4.z, l4.z);
        split_val(f.w, h4.w, l4.w);
        *(ushort4*)(H + i) = h4;
        *(ushort4*)(L + i) = l4;
    }
}

// ---- zero the 63-column left pad of the transposed V buffers ----
__global__ __launch_bounds__(256) void zero_pad(
    unsigned short* __restrict__ VTH, unsigned short* __restrict__ VTL, int vtw)
{
    int i = blockIdx.x * blockDim.x + threadIdx.x;
    if (i < 512 * 63) {
        int r = i / 63, c = i % 63;
        VTH[(size_t)r * vtw + c] = 0;
        VTL[(size_t)r * vtw + c] = 0;
    }
}

// ---- fused Q/K/V^T projection GEMM, double-buffered, split-bf16 K-concat ----
// All tiles BM=128 x BN=64, BK=64, 24 K-steps ([Ah|Ah|Al] @ [Bh|Bl|Bh]).
// Blocks [0, 2*NQK): C = x @ Wq^T / x @ Wk^T  -> QH/QL, KH/KL [T][512].
// Blocks [2*NQK, +NVT): C = Wv @ x^T = V^T    -> VTH/VTL [512][vtw], +63 pad,
//   coalesced along t (col dim).
__global__ __launch_bounds__(256) void gemm_qkvt(
    const unsigned short* __restrict__ xh, const unsigned short* __restrict__ xl,
    const unsigned short* __restrict__ wqh, const unsigned short* __restrict__ wql,
    const unsigned short* __restrict__ wkh, const unsigned short* __restrict__ wkl,
    const unsigned short* __restrict__ wvh, const unsigned short* __restrict__ wvl,
    unsigned short* __restrict__ QHo, unsigned short* __restrict__ QLo,
    unsigned short* __restrict__ KHo, unsigned short* __restrict__ KLo,
    unsigned short* __restrict__ VTH, unsigned short* __restrict__ VTL,
    int T, int vtw)
{
    constexpr int ABYTES = 128 * 128;                 // A tile bytes
    __shared__ unsigned char lds[2][(128 + 64) * 128]; // 2 x 24 KB

    const int tid  = threadIdx.x;
    const int wid  = tid >> 6;
    const int lane = tid & 63;
    const int wr = wid >> 1, wc = wid & 1;

    const int NQK = 8 * (T / 128);
    const int id  = blockIdx.x;
    const unsigned short *Ah, *Al, *Bh, *Bl;
    unsigned short *OH_, *OL_;
    int m0, n0;
    bool vt;
    if (id < 2 * NQK) {
        vt = false;
        const int zq  = id / NQK;           // 0 = Q, 1 = K
        const int rem = id % NQK;
        n0 = (rem & 7) * 64;                // 512 / 64
        m0 = (rem >> 3) * 128;              // T / 128
        Ah = xh; Al = xl;
        Bh = zq ? wkh : wqh;  Bl = zq ? wkl : wql;
        OH_ = zq ? KHo : QHo; OL_ = zq ? KLo : QLo;
    } else {
        vt = true;
        const int rem = id - 2 * NQK;
        const int nx  = T / 64;
        n0 = (rem % nx) * 64;               // t dim
        m0 = (rem / nx) * 128;              // d dim (512 / 128 = 4)
        Ah = wvh; Al = wvl;
        Bh = xh;  Bl = xl;
        OH_ = VTH; OL_ = VTL;
    }

    f32x4 acc[4][2];
    #pragma unroll
    for (int i = 0; i < 4; ++i) {
        acc[i][0] = (f32x4){0.f, 0.f, 0.f, 0.f};
        acc[i][1] = (f32x4){0.f, 0.f, 0.f, 0.f};
    }

    auto stage = [&](int buf, int ks) {
        const int rg = ks >> 3;
        const int k0 = (ks & 7) << 6;
        const unsigned short* As = (rg < 2) ? Ah : Al;
        const unsigned short* Bs = (rg == 1) ? Bl : Bh;
        #pragma unroll
        for (int j = 0; j < 6; ++j) {                  // 24 insts / 4 waves
            const int o  = (wid * 6 + j) << 10;        // wave-uniform LDS base
            const int li = o + lane * 16;
            const void* g;
            if (li < ABYTES) {        // uniform per inst (1KB-aligned boundary)
                const int r  = li >> 7;
                const int kb = (li & 127) ^ ((r & 7) << 4);   // inverse swizzle
                g = As + (size_t)(m0 + r) * 512 + k0 + (kb >> 1);
            } else {
                const int lb = li - ABYTES;
                const int r  = lb >> 7;
                const int kb = (lb & 127) ^ ((r & 7) << 4);
                g = Bs + (size_t)(n0 + r) * 512 + k0 + (kb >> 1);
            }
            gload16(g, &lds[buf][o], lane);
        }
    };

    // double-buffered K-loop: stage(next) issued BEFORE compute(cur);
    // the single barrier drains vmcnt AFTER compute covered the latency.
    stage(0, 0);
    __syncthreads();
    int cur = 0;
    for (int ks = 0; ks < 24; ++ks) {
        if (ks < 23) stage(cur ^ 1, ks + 1);
        #pragma unroll
        for (int ksub = 0; ksub < 2; ++ksub) {
            const int kbb = (ksub << 6) + ((lane >> 4) << 4);
            bf16frag af[4], bf[2];
            #pragma unroll
            for (int mt = 0; mt < 4; ++mt) {
                const int r = wr * 64 + mt * 16 + (lane & 15);
                af[mt] = *(const bf16frag*)(&lds[cur][0] + r * 128 + (kbb ^ ((r & 7) << 4)));
            }
            #pragma unroll
            for (int nt = 0; nt < 2; ++nt) {
                const int r = wc * 32 + nt * 16 + (lane & 15);
                bf[nt] = *(const bf16frag*)(&lds[cur][0] + ABYTES + r * 128 + (kbb ^ ((r & 7) << 4)));
            }
            #pragma unroll
            for (int mt = 0; mt < 4; ++mt)
                #pragma unroll
                for (int nt = 0; nt < 2; ++nt)
                    acc[mt][nt] = __builtin_amdgcn_mfma_f32_16x16x32_bf16(
                        af[mt], bf[nt], acc[mt][nt], 0, 0, 0);
        }
        __syncthreads();
        cur ^= 1;
    }

    // C/D layout (HW-verified): col = lane&15, row = (lane>>4)*4 + j
    const int rbase = (lane >> 4) * 4;
    #pragma unroll
    for (int mt = 0; mt < 4; ++mt)
        #pragma unroll
        for (int nt = 0; nt < 2; ++nt) {
            const int col = n0 + wc * 32 + nt * 16 + (lane & 15);
            #pragma unroll
            for (int j = 0; j < 4; ++j) {
                const int row = m0 + wr * 64 + mt * 16 + rbase + j;
                unsigned short hh, ll;
                split_val(acc[mt][nt][j], hh, ll);
                if (!vt) {
                    OH_[(size_t)row * 512 + col] = hh;
                    OL_[(size_t)row * 512 + col] = ll;
                } else {   // V^T: row = d, col = t; contiguous across lanes
                    OH_[(size_t)row * vtw + 63 + col] = hh;
                    OL_[(size_t)row * vtw + 63 + col] = ll;
                }
            }
        }
}

// ---- output projection GEMM: C[T][512] fp32 = ab @ Wo^T, double-buffered ----
__global__ __launch_bounds__(256) void gemm_out(
    const unsigned short* __restrict__ Ah, const unsigned short* __restrict__ Al,
    const unsigned short* __restrict__ Wh, const unsigned short* __restrict__ Wl,
    float* __restrict__ C)
{
    constexpr int ABYTES = 64 * 128;                  // 8 KB
    __shared__ unsigned char lds[2][(64 + 64) * 128]; // 2 x 16 KB

    const int tid  = threadIdx.x;
    const int wid  = tid >> 6;
    const int lane = tid & 63;
    const int wr = wid >> 1, wc = wid & 1;
    const int m0 = blockIdx.y * 64;
    const int n0 = blockIdx.x * 64;

    f32x4 acc[2][2];
    #pragma unroll
    for (int i = 0; i < 2; ++i) {
        acc[i][0] = (f32x4){0.f, 0.f, 0.f, 0.f};
        acc[i][1] = (f32x4){0.f, 0.f, 0.f, 0.f};
    }

    auto stage = [&](int buf, int ks) {
        const int rg = ks >> 3;
        const int k0 = (ks & 7) << 6;
        const unsigned short* As = (rg < 2) ? Ah : Al;
        const unsigned short* Bs = (rg == 1) ? Wl : Wh;
        #pragma unroll
        for (int j = 0; j < 4; ++j) {                  // 16 insts / 4 waves
            const int o  = (wid * 4 + j) << 10;
            const int li = o + lane * 16;
            const void* g;
            if (li < ABYTES) {
                const int r  = li >> 7;
                const int kb = (li & 127) ^ ((r & 7) << 4);
                g = As + (size_t)(m0 + r) * 512 + k0 + (kb >> 1);
            } else {
                const int lb = li - ABYTES;
                const int r  = lb >> 7;
                const int kb = (lb & 127) ^ ((r & 7) << 4);
                g = Bs + (size_t)(n0 + r) * 512 + k0 + (kb >> 1);
            }
            gload16(g, &lds[buf][o], lane);
        }
    };

    stage(0, 0);
    __syncthreads();
    int cur = 0;
    for (int ks = 0; ks < 24; ++ks) {
        if (ks < 23) stage(cur ^ 1, ks + 1);
        #pragma unroll
        for (int ksub = 0; ksub < 2; ++ksub) {
            const int kbb = (ksub << 6) + ((lane >> 4) << 4);
            bf16frag af[2], bf[2];
            #pragma unroll
            for (int mt = 0; mt < 2; ++mt) {
                const int r = wr * 32 + mt * 16 + (lane & 15);
                af[mt] = *(const bf16frag*)(&lds[cur][0] + r * 128 + (kbb ^ ((r & 7) << 4)));
            }
            #pragma unroll
            for (int nt = 0; nt < 2; ++nt) {
                const int r = wc * 32 + nt * 16 + (lane & 15);
                bf[nt] = *(const bf16frag*)(&lds[cur][0] + ABYTES + r * 128 + (kbb ^ ((r & 7) << 4)));
            }
            #pragma unroll
            for (int mt = 0; mt < 2; ++mt)
                #pragma unroll
                for (int nt = 0; nt < 2; ++nt)
                    acc[mt][nt] = __builtin_amdgcn_mfma_f32_16x16x32_bf16(
                        af[mt], bf[nt], acc[mt][nt], 0, 0, 0);
        }
        __syncthreads();
        cur ^= 1;
    }

    const int rbase = (lane >> 4) * 4;
    #pragma unroll
    for (int mt = 0; mt < 2; ++mt)
        #pragma unroll
        for (int nt = 0; nt < 2; ++nt) {
            const int col = n0 + wc * 32 + nt * 16 + (lane & 15);
            #pragma unroll
            for (int j = 0; j < 4; ++j) {
                const int row = m0 + wr * 32 + mt * 16 + rbase + j;
                C[(size_t)row * 512 + col] = acc[mt][nt][j];
            }
        }
}

// ---- MFMA windowed attention (byte-identical to round 12, validated) ----
__global__ __launch_bounds__(128) void swattn5(
    const unsigned short* __restrict__ QH, const unsigned short* __restrict__ QL,
    const unsigned short* __restrict__ KH, const unsigned short* __restrict__ KL,
    const unsigned short* __restrict__ VTH, const unsigned short* __restrict__ VTL,
    unsigned short* __restrict__ OH, unsigned short* __restrict__ OL, int T)
{
    __shared__ unsigned short KsH[96 * 88], KsL[96 * 88];    // rows w, pad 88
    __shared__ unsigned short VtH[64 * 104], VtL[64 * 104];  // rows d, pad 104
    __shared__ unsigned short PsH[32 * 104], PsL[32 * 104];  // rows q, pad 104

    const int h   = blockIdx.x & 7;
    const int t0  = (blockIdx.x >> 3) * 32;
    const int kt0 = t0 - 63;
    const int tid = threadIdx.x;
    const int vtw = T + 64;

    {
        const int c = tid & 7;
        for (int r = tid >> 3; r < 96; r += 16) {
            const int kt = kt0 + r;
            u16x8 kh = {0,0,0,0,0,0,0,0}, kl = {0,0,0,0,0,0,0,0};
            if (kt >= 0 && r < 95) {
                const size_t off = (size_t)kt * 512 + h * 64 + c * 8;
                kh = *(const u16x8*)(KH + off);
                kl = *(const u16x8*)(KL + off);
            }
            *(u16x8*)&KsH[r * 88 + c * 8] = kh;
            *(u16x8*)&KsL[r * 88 + c * 8] = kl;
        }
    }
    for (int i = tid; i < 64 * 12; i += 128) {
        const int d = i / 12, c = i % 12;
        const size_t off = (size_t)(h * 64 + d) * vtw + t0 + c * 8;
        *(u16x8*)&VtH[d * 104 + c * 8] = *(const u16x8*)(VTH + off);
        *(u16x8*)&VtL[d * 104 + c * 8] = *(const u16x8*)(VTL + off);
    }
    __syncthreads();

    const int wid  = tid >> 6;
    const int lane = tid & 63;
    const int lr = lane & 15;
    const int lg = lane >> 4;

    bf16frag qfh[2], qfl[2];
    {
        const size_t base = (size_t)(t0 + wid * 16 + lr) * 512 + h * 64 + lg * 8;
        qfh[0] = *(const bf16frag*)(QH + base);
        qfh[1] = *(const bf16frag*)(QH + base + 32);
        qfl[0] = *(const bf16frag*)(QL + base);
        qfl[1] = *(const bf16frag*)(QL + base + 32);
    }

    f32x4 s[6];
    #pragma unroll
    for (int wt = 0; wt < 6; ++wt) s[wt] = (f32x4){0.f, 0.f, 0.f, 0.f};
    #pragma unroll
    for (int ksub = 0; ksub < 2; ++ksub) {
        #pragma unroll
        for (int wt = 0; wt < 6; ++wt) {
            const int a = (wt * 16 + lr) * 88 + lg * 8 + ksub * 32;
            bf16frag akh = *(const bf16frag*)&KsH[a];
            bf16frag akl = *(const bf16frag*)&KsL[a];
            s[wt] = __builtin_amdgcn_mfma_f32_16x16x32_bf16(akh, qfh[ksub], s[wt], 0, 0, 0);
            s[wt] = __builtin_amdgcn_mfma_f32_16x16x32_bf16(akh, qfl[ksub], s[wt], 0, 0, 0);
            s[wt] = __builtin_amdgcn_mfma_f32_16x16x32_bf16(akl, qfh[ksub], s[wt], 0, 0, 0);
        }
    }

    const int q_local = wid * 16 + lr;
    float sc[6][4];
    float mx = -3e38f;
    #pragma unroll
    for (int wt = 0; wt < 6; ++wt)
        #pragma unroll
        for (int j = 0; j < 4; ++j) {
            const int w = wt * 16 + lg * 4 + j;
            const bool valid = (w >= q_local) && (w <= q_local + 63) && (kt0 + w >= 0);
            sc[wt][j] = valid ? s[wt][j] * 0.125f : -3e38f;
            mx = fmaxf(mx, sc[wt][j]);
        }
    mx = fmaxf(mx, __shfl_xor(mx, 16));
    mx = fmaxf(mx, __shfl_xor(mx, 32));
    float sum = 0.f;
    #pragma unroll
    for (int wt = 0; wt < 6; ++wt)
        #pragma unroll
        for (int j = 0; j < 4; ++j) {
            sc[wt][j] = __expf(sc[wt][j] - mx);
            sum += sc[wt][j];
        }
    sum += __shfl_xor(sum, 16);
    sum += __shfl_xor(sum, 32);
    const float inv = 1.f / sum;

    #pragma unroll
    for (int wt = 0; wt < 6; ++wt) {
        ushort4 ph, pl;
        unsigned short hh, ll;
        split_val(sc[wt][0] * inv, hh, ll); ph.x = hh; pl.x = ll;
        split_val(sc[wt][1] * inv, hh, ll); ph.y = hh; pl.y = ll;
        split_val(sc[wt][2] * inv, hh, ll); ph.z = hh; pl.z = ll;
        split_val(sc[wt][3] * inv, hh, ll); ph.w = hh; pl.w = ll;
        const int col = wt * 16 + lg * 4;
        *(ushort4*)&PsH[q_local * 104 + col] = ph;
        *(ushort4*)&PsL[q_local * 104 + col] = pl;
    }

    f32x4 oa[4];
    #pragma unroll
    for (int dt = 0; dt < 4; ++dt) oa[dt] = (f32x4){0.f, 0.f, 0.f, 0.f};
    #pragma unroll
    for (int ks = 0; ks < 3; ++ks) {
        const int ka = lg * 8 + ks * 32;
        bf16frag pah = *(const bf16frag*)&PsH[(wid * 16 + lr) * 104 + ka];
        bf16frag pal = *(const bf16frag*)&PsL[(wid * 16 + lr) * 104 + ka];
        #pragma unroll
        for (int dt = 0; dt < 4; ++dt) {
            const int a = (dt * 16 + lr) * 104 + ka;
            bf16frag bvh = *(const bf16frag*)&VtH[a];
            bf16frag bvl = *(const bf16frag*)&VtL[a];
            oa[dt] = __builtin_amdgcn_mfma_f32_16x16x32_bf16(pah, bvh, oa[dt], 0, 0, 0);
            oa[dt] = __builtin_amdgcn_mfma_f32_16x16x32_bf16(pal, bvh, oa[dt], 0, 0, 0);
            oa[dt] = __builtin_amdgcn_mfma_f32_16x16x32_bf16(pah, bvl, oa[dt], 0, 0, 0);
        }
    }

    #pragma unroll
    for (int dt = 0; dt < 4; ++dt) {
        const int d = dt * 16 + lr;
        #pragma unroll
        for (int j = 0; j < 4; ++j) {
            const int t = t0 + wid * 16 + lg * 4 + j;
            unsigned short hh, ll;
            split_val(oa[dt][j], hh, ll);
            const size_t oi = (size_t)t * 512 + h * 64 + d;
            OH[oi] = hh;
            OL[oi] = ll;
        }
    }
}

extern "C" void kernel_launch(void* const* d_in, const int* in_sizes, int n_in,
                              void* d_out, int out_size, void* d_ws, size_t ws_size,
                              hipStream_t stream) {
    const float* x  = (const float*)d_in[0];
    const float* Wq = (const float*)d_in[1];
    const float* Wk = (const float*)d_in[2];
    const float* Wv = (const float*)d_in[3];
    const float* Wo = (const float*)d_in[4];
    float* out = (float*)d_out;

    const int D = 512;
    const int T = in_sizes[0] / D;        // 4096
    const size_t tdf = (size_t)T * D;     // 2,097,152
    const size_t wsz = (size_t)D * D;     //   262,144
    const int vtw = T + 64;
    const size_t vts = (size_t)D * vtw;

    unsigned short* qh  = (unsigned short*)d_ws;
    unsigned short* ql  = qh + tdf;
    unsigned short* kh  = ql + tdf;
    unsigned short* kl  = kh + tdf;
    unsigned short* vth = kl + tdf;
    unsigned short* vtl = vth + vts;
    unsigned short* abh = vtl + vts;
    unsigned short* abl = abh + tdf;
    unsigned short* xh  = abl + tdf;
    unsigned short* xl  = xh + tdf;
    unsigned short* wqh = xl + tdf;
    unsigned short* wql = wqh + wsz;
    unsigned short* wkh = wql + wsz;
    unsigned short* wkl = wkh + wsz;
    unsigned short* wvh = wkl + wsz;
    unsigned short* wvl = wvh + wsz;
    unsigned short* woh = wvl + wsz;
    unsigned short* wol = woh + wsz;
    // ws use ≈ 46 MB

    dim3 blk(256);
    split5<<<dim3(256, 1, 5), blk, 0, stream>>>(
        x, Wq, Wk, Wv, Wo, xh, xl, wqh, wql, wkh, wkl, wvh, wvl, woh, wol,
        (int)tdf, (int)wsz);

    zero_pad<<<dim3((512 * 63 + 255) / 256), blk, 0, stream>>>(vth, vtl, vtw);

    // fused Q/K/V^T: 2*NQK + NVT blocks = 512 + 256 = 768
    const int NQK = 8 * (T / 128);
    const int NVT = (T / 64) * (D / 128);
    gemm_qkvt<<<dim3(2 * NQK + NVT), blk, 0, stream>>>(
        xh, xl, wqh, wql, wkh, wkl, wvh, wvl,
        qh, ql, kh, kl, vth, vtl, T, vtw);

    // attention: 8 heads x T/32 = 1024 blocks x 128 thr
    swattn5<<<dim3(8 * T / 32), dim3(128), 0, stream>>>(
        qh, ql, kh, kl, vth, vtl, abh, abl, T);

    // out-proj: fp32 to d_out, 8 x 64 = 512 blocks
    gemm_out<<<dim3(D / 64, T / 64), blk, 0, stream>>>(
        abh, abl, woh, wol, out);
}

// Round 14
// 134.437 us; speedup vs baseline: 1.6643x; 1.0440x over previous
//
#include <hip/hip_runtime.h>
#include <hip/hip_bf16.h>
#include <math.h>

// Round 14:
//  - GEMMs: counted-vmcnt + RAW s_barrier double-buffer (prefetch survives the
//    barrier; __syncthreads' vmcnt(0) drain was defeating round-13's dbuf).
//  - XCD-chunked block-id swizzle in both GEMMs (tile-sharing neighbors -> same L2).
//  - zero_pad fused into qkvt's n0==0 V^T blocks (one fewer launch).
//  - swattn5 / split5: byte-identical to round 13 (validated).

typedef __attribute__((ext_vector_type(8))) short bf16frag;   // 8 bf16 = 16 B
typedef __attribute__((ext_vector_type(4))) float f32x4;
typedef __attribute__((ext_vector_type(8))) unsigned short u16x8;

#if defined(__has_builtin)
#if __has_builtin(__builtin_amdgcn_global_load_lds)
#define HAVE_GLOAD_LDS 1
#endif
#endif

__device__ inline void gload16(const void* g, void* l, int lane) {
#ifdef HAVE_GLOAD_LDS
    __builtin_amdgcn_global_load_lds(
        (const __attribute__((address_space(1))) void*)g,
        (__attribute__((address_space(3))) void*)l, 16, 0, 0);
#else
    *(bf16frag*)((char*)l + lane * 16) = *(const bf16frag*)g;
#endif
}

__device__ inline unsigned short bf16_rne(float f) {
    unsigned int u = __float_as_uint(f);
    unsigned int r = u + 0x7fffu + ((u >> 16) & 1u);
    return (unsigned short)(r >> 16);
}

__device__ inline void split_val(float f, unsigned short& h, unsigned short& l) {
    h = bf16_rne(f);
    float hf = __uint_as_float(((unsigned int)h) << 16);
    float lf = f - hf;
    l = bf16_rne(lf);
}

// ---- fp32 -> (hi, lo) bf16 split: x + 4 weight matrices in one launch ----
__global__ __launch_bounds__(256) void split5(
    const float* __restrict__ x, const float* __restrict__ wq, const float* __restrict__ wk,
    const float* __restrict__ wv, const float* __restrict__ wo,
    unsigned short* xh, unsigned short* xl, unsigned short* qh, unsigned short* ql,
    unsigned short* kh, unsigned short* kl, unsigned short* vh, unsigned short* vl,
    unsigned short* oh, unsigned short* ol, int nx, int nw)
{
    const float* src; unsigned short *H, *L; int n;
    switch (blockIdx.z) {
        case 0: src = x;  H = xh; L = xl; n = nx; break;
        case 1: src = wq; H = qh; L = ql; n = nw; break;
        case 2: src = wk; H = kh; L = kl; n = nw; break;
        case 3: src = wv; H = vh; L = vl; n = nw; break;
        default: src = wo; H = oh; L = ol; n = nw; break;
    }
    int stride = gridDim.x * blockDim.x * 4;
    for (int i = (blockIdx.x * blockDim.x + threadIdx.x) * 4; i < n; i += stride) {
        float4 f = *(const float4*)(src + i);
        ushort4 h4, l4;
        split_val(f.x, h4.x, l4.x);
        split_val(f.y, h4.y, l4.y);
        split_val(f.z, h4.z, l4.z);
        split_val(f.w, h4.w, l4.w);
        *(ushort4*)(H + i) = h4;
        *(ushort4*)(L + i) = l4;
    }
}

// ---- fused Q/K/V^T projection GEMM, counted-vmcnt dbuf, split-bf16 K-concat ----
// All tiles BM=128 x BN=64, BK=64, 24 K-steps ([Ah|Ah|Al] @ [Bh|Bl|Bh]).
// orig-id [0, 2*NQK): C = x @ Wq^T / x @ Wk^T -> QH/QL, KH/KL [T][512].
// orig-id [2*NQK, +NVT): C = Wv @ x^T = V^T   -> VTH/VTL [512][vtw] (+63 pad).
// n0==0 V^T blocks also zero the 63-col left pad (zero_pad kernel fused).
__global__ __launch_bounds__(256) void gemm_qkvt(
    const unsigned short* __restrict__ xh, const unsigned short* __restrict__ xl,
    const unsigned short* __restrict__ wqh, const unsigned short* __restrict__ wql,
    const unsigned short* __restrict__ wkh, const unsigned short* __restrict__ wkl,
    const unsigned short* __restrict__ wvh, const unsigned short* __restrict__ wvl,
    unsigned short* __restrict__ QHo, unsigned short* __restrict__ QLo,
    unsigned short* __restrict__ KHo, unsigned short* __restrict__ KLo,
    unsigned short* __restrict__ VTH, unsigned short* __restrict__ VTL,
    int T, int vtw)
{
    constexpr int ABYTES = 128 * 128;                  // A tile bytes
    __shared__ unsigned char lds[2][(128 + 64) * 128]; // 2 x 24 KB

    const int tid  = threadIdx.x;
    const int wid  = tid >> 6;
    const int lane = tid & 63;
    const int wr = wid >> 1, wc = wid & 1;

    // XCD-chunked bijective swizzle: hw-consecutive blocks on one XCD get a
    // contiguous orig-id chunk -> n-neighbors sharing the A-tile share an L2.
    const int chunk = gridDim.x >> 3;
    const int id = (blockIdx.x & 7) * chunk + (blockIdx.x >> 3);

    const int NQK = 8 * (T / 128);
    const unsigned short *Ah, *Al, *Bh, *Bl;
    unsigned short *OH_, *OL_;
    int m0, n0;
    bool vt;
    if (id < 2 * NQK) {
        vt = false;
        const int zq  = id / NQK;           // 0 = Q, 1 = K
        const int rem = id % NQK;
        n0 = (rem & 7) * 64;
        m0 = (rem >> 3) * 128;
        Ah = xh; Al = xl;
        Bh = zq ? wkh : wqh;  Bl = zq ? wkl : wql;
        OH_ = zq ? KHo : QHo; OL_ = zq ? KLo : QLo;
    } else {
        vt = true;
        const int rem = id - 2 * NQK;
        const int nx  = T / 64;
        n0 = (rem % nx) * 64;               // t dim
        m0 = (rem / nx) * 128;              // d dim
        Ah = wvh; Al = wvl;
        Bh = xh;  Bl = xl;
        OH_ = VTH; OL_ = VTL;
        if (n0 == 0) {                      // fused zero_pad: rows m0..m0+127
            for (int i = tid; i < 128 * 63; i += 256) {
                const int r = i / 63, c = i % 63;
                VTH[(size_t)(m0 + r) * vtw + c] = 0;
                VTL[(size_t)(m0 + r) * vtw + c] = 0;
            }
        }
    }

    f32x4 acc[4][2];
    #pragma unroll
    for (int i = 0; i < 4; ++i) {
        acc[i][0] = (f32x4){0.f, 0.f, 0.f, 0.f};
        acc[i][1] = (f32x4){0.f, 0.f, 0.f, 0.f};
    }

    auto stage = [&](int buf, int ks) {
        const int rg = ks >> 3;
        const int k0 = (ks & 7) << 6;
        const unsigned short* As = (rg < 2) ? Ah : Al;
        const unsigned short* Bs = (rg == 1) ? Bl : Bh;
        #pragma unroll
        for (int j = 0; j < 6; ++j) {                  // 24 insts / 4 waves
            const int o  = (wid * 6 + j) << 10;        // wave-uniform LDS base
            const int li = o + lane * 16;
            const void* g;
            if (li < ABYTES) {
                const int r  = li >> 7;
                const int kb = (li & 127) ^ ((r & 7) << 4);   // inverse swizzle
                g = As + (size_t)(m0 + r) * 512 + k0 + (kb >> 1);
            } else {
                const int lb = li - ABYTES;
                const int r  = lb >> 7;
                const int kb = (lb & 127) ^ ((r & 7) << 4);
                g = Bs + (size_t)(n0 + r) * 512 + k0 + (kb >> 1);
            }
            gload16(g, &lds[buf][o], lane);
        }
    };

    // counted-vmcnt raw-barrier dbuf: next-tile loads stay in flight across
    // the barrier; vmcnt(6) waits only for the CURRENT tile's (older) loads.
    stage(0, 0);
    asm volatile("s_waitcnt vmcnt(0)" ::: "memory");
    __builtin_amdgcn_s_barrier();
    int cur = 0;
    for (int ks = 0; ks < 24; ++ks) {
        if (ks < 23) {
            stage(cur ^ 1, ks + 1);
            asm volatile("s_waitcnt vmcnt(6)" ::: "memory");
        } else {
            asm volatile("s_waitcnt vmcnt(0)" ::: "memory");
        }
        __builtin_amdgcn_s_barrier();      // all waves' cur-tile loads landed
        #pragma unroll
        for (int ksub = 0; ksub < 2; ++ksub) {
            const int kbb = (ksub << 6) + ((lane >> 4) << 4);
            bf16frag af[4], bf[2];
            #pragma unroll
            for (int mt = 0; mt < 4; ++mt) {
                const int r = wr * 64 + mt * 16 + (lane & 15);
                af[mt] = *(const bf16frag*)(&lds[cur][0] + r * 128 + (kbb ^ ((r & 7) << 4)));
            }
            #pragma unroll
            for (int nt = 0; nt < 2; ++nt) {
                const int r = wc * 32 + nt * 16 + (lane & 15);
                bf[nt] = *(const bf16frag*)(&lds[cur][0] + ABYTES + r * 128 + (kbb ^ ((r & 7) << 4)));
            }
            #pragma unroll
            for (int mt = 0; mt < 4; ++mt)
                #pragma unroll
                for (int nt = 0; nt < 2; ++nt)
                    acc[mt][nt] = __builtin_amdgcn_mfma_f32_16x16x32_bf16(
                        af[mt], bf[nt], acc[mt][nt], 0, 0, 0);
        }
        __builtin_amdgcn_s_barrier();      // all reads of cur done before overwrite
        cur ^= 1;
    }

    // C/D layout (HW-verified): col = lane&15, row = (lane>>4)*4 + j
    const int rbase = (lane >> 4) * 4;
    #pragma unroll
    for (int mt = 0; mt < 4; ++mt)
        #pragma unroll
        for (int nt = 0; nt < 2; ++nt) {
            const int col = n0 + wc * 32 + nt * 16 + (lane & 15);
            #pragma unroll
            for (int j = 0; j < 4; ++j) {
                const int row = m0 + wr * 64 + mt * 16 + rbase + j;
                unsigned short hh, ll;
                split_val(acc[mt][nt][j], hh, ll);
                if (!vt) {
                    OH_[(size_t)row * 512 + col] = hh;
                    OL_[(size_t)row * 512 + col] = ll;
                } else {   // V^T: row = d, col = t; contiguous across lanes
                    OH_[(size_t)row * vtw + 63 + col] = hh;
                    OL_[(size_t)row * vtw + 63 + col] = ll;
                }
            }
        }
}

// ---- output projection GEMM: C[T][512] fp32 = ab @ Wo^T, counted-vmcnt dbuf ----
__global__ __launch_bounds__(256) void gemm_out(
    const unsigned short* __restrict__ Ah, const unsigned short* __restrict__ Al,
    const unsigned short* __restrict__ Wh, const unsigned short* __restrict__ Wl,
    float* __restrict__ C, int T)
{
    constexpr int ABYTES = 64 * 128;                  // 8 KB
    __shared__ unsigned char lds[2][(64 + 64) * 128]; // 2 x 16 KB

    const int tid  = threadIdx.x;
    const int wid  = tid >> 6;
    const int lane = tid & 63;
    const int wr = wid >> 1, wc = wid & 1;

    // XCD-chunked swizzle; orig decode: n fastest (8 n-blocks share the A-tile)
    const int chunk = gridDim.x >> 3;
    const int b = (blockIdx.x & 7) * chunk + (blockIdx.x >> 3);
    const int n0 = (b & 7) * 64;
    const int m0 = (b >> 3) * 64;

    f32x4 acc[2][2];
    #pragma unroll
    for (int i = 0; i < 2; ++i) {
        acc[i][0] = (f32x4){0.f, 0.f, 0.f, 0.f};
        acc[i][1] = (f32x4){0.f, 0.f, 0.f, 0.f};
    }

    auto stage = [&](int buf, int ks) {
        const int rg = ks >> 3;
        const int k0 = (ks & 7) << 6;
        const unsigned short* As = (rg < 2) ? Ah : Al;
        const unsigned short* Bs = (rg == 1) ? Wl : Wh;
        #pragma unroll
        for (int j = 0; j < 4; ++j) {                  // 16 insts / 4 waves
            const int o  = (wid * 4 + j) << 10;
            const int li = o + lane * 16;
            const void* g;
            if (li < ABYTES) {
                const int r  = li >> 7;
                const int kb = (li & 127) ^ ((r & 7) << 4);
                g = As + (size_t)(m0 + r) * 512 + k0 + (kb >> 1);
            } else {
                const int lb = li - ABYTES;
                const int r  = lb >> 7;
                const int kb = (lb & 127) ^ ((r & 7) << 4);
                g = Bs + (size_t)(n0 + r) * 512 + k0 + (kb >> 1);
            }
            gload16(g, &lds[buf][o], lane);
        }
    };

    stage(0, 0);
    asm volatile("s_waitcnt vmcnt(0)" ::: "memory");
    __builtin_amdgcn_s_barrier();
    int cur = 0;
    for (int ks = 0; ks < 24; ++ks) {
        if (ks < 23) {
            stage(cur ^ 1, ks + 1);
            asm volatile("s_waitcnt vmcnt(4)" ::: "memory");
        } else {
            asm volatile("s_waitcnt vmcnt(0)" ::: "memory");
        }
        __builtin_amdgcn_s_barrier();
        #pragma unroll
        for (int ksub = 0; ksub < 2; ++ksub) {
            const int kbb = (ksub << 6) + ((lane >> 4) << 4);
            bf16frag af[2], bf[2];
            #pragma unroll
            for (int mt = 0; mt < 2; ++mt) {
                const int r = wr * 32 + mt * 16 + (lane & 15);
                af[mt] = *(const bf16frag*)(&lds[cur][0] + r * 128 + (kbb ^ ((r & 7) << 4)));
            }
            #pragma unroll
            for (int nt = 0; nt < 2; ++nt) {
                const int r = wc * 32 + nt * 16 + (lane & 15);
                bf[nt] = *(const bf16frag*)(&lds[cur][0] + ABYTES + r * 128 + (kbb ^ ((r & 7) << 4)));
            }
            #pragma unroll
            for (int mt = 0; mt < 2; ++mt)
                #pragma unroll
                for (int nt = 0; nt < 2; ++nt)
                    acc[mt][nt] = __builtin_amdgcn_mfma_f32_16x16x32_bf16(
                        af[mt], bf[nt], acc[mt][nt], 0, 0, 0);
        }
        __builtin_amdgcn_s_barrier();
        cur ^= 1;
    }

    const int rbase = (lane >> 4) * 4;
    #pragma unroll
    for (int mt = 0; mt < 2; ++mt)
        #pragma unroll
        for (int nt = 0; nt < 2; ++nt) {
            const int col = n0 + wc * 32 + nt * 16 + (lane & 15);
            #pragma unroll
            for (int j = 0; j < 4; ++j) {
                const int row = m0 + wr * 32 + mt * 16 + rbase + j;
                C[(size_t)row * 512 + col] = acc[mt][nt][j];
            }
        }
}

// ---- MFMA windowed attention (byte-identical to rounds 12/13, validated) ----
__global__ __launch_bounds__(128) void swattn5(
    const unsigned short* __restrict__ QH, const unsigned short* __restrict__ QL,
    const unsigned short* __restrict__ KH, const unsigned short* __restrict__ KL,
    const unsigned short* __restrict__ VTH, const unsigned short* __restrict__ VTL,
    unsigned short* __restrict__ OH, unsigned short* __restrict__ OL, int T)
{
    __shared__ unsigned short KsH[96 * 88], KsL[96 * 88];    // rows w, pad 88
    __shared__ unsigned short VtH[64 * 104], VtL[64 * 104];  // rows d, pad 104
    __shared__ unsigned short PsH[32 * 104], PsL[32 * 104];  // rows q, pad 104

    const int h   = blockIdx.x & 7;
    const int t0  = (blockIdx.x >> 3) * 32;
    const int kt0 = t0 - 63;
    const int tid = threadIdx.x;
    const int vtw = T + 64;

    {
        const int c = tid & 7;
        for (int r = tid >> 3; r < 96; r += 16) {
            const int kt = kt0 + r;
            u16x8 kh = {0,0,0,0,0,0,0,0}, kl = {0,0,0,0,0,0,0,0};
            if (kt >= 0 && r < 95) {
                const size_t off = (size_t)kt * 512 + h * 64 + c * 8;
                kh = *(const u16x8*)(KH + off);
                kl = *(const u16x8*)(KL + off);
            }
            *(u16x8*)&KsH[r * 88 + c * 8] = kh;
            *(u16x8*)&KsL[r * 88 + c * 8] = kl;
        }
    }
    for (int i = tid; i < 64 * 12; i += 128) {
        const int d = i / 12, c = i % 12;
        const size_t off = (size_t)(h * 64 + d) * vtw + t0 + c * 8;
        *(u16x8*)&VtH[d * 104 + c * 8] = *(const u16x8*)(VTH + off);
        *(u16x8*)&VtL[d * 104 + c * 8] = *(const u16x8*)(VTL + off);
    }
    __syncthreads();

    const int wid  = tid >> 6;
    const int lane = tid & 63;
    const int lr = lane & 15;
    const int lg = lane >> 4;

    bf16frag qfh[2], qfl[2];
    {
        const size_t base = (size_t)(t0 + wid * 16 + lr) * 512 + h * 64 + lg * 8;
        qfh[0] = *(const bf16frag*)(QH + base);
        qfh[1] = *(const bf16frag*)(QH + base + 32);
        qfl[0] = *(const bf16frag*)(QL + base);
        qfl[1] = *(const bf16frag*)(QL + base + 32);
    }

    f32x4 s[6];
    #pragma unroll
    for (int wt = 0; wt < 6; ++wt) s[wt] = (f32x4){0.f, 0.f, 0.f, 0.f};
    #pragma unroll
    for (int ksub = 0; ksub < 2; ++ksub) {
        #pragma unroll
        for (int wt = 0; wt < 6; ++wt) {
            const int a = (wt * 16 + lr) * 88 + lg * 8 + ksub * 32;
            bf16frag akh = *(const bf16frag*)&KsH[a];
            bf16frag akl = *(const bf16frag*)&KsL[a];
            s[wt] = __builtin_amdgcn_mfma_f32_16x16x32_bf16(akh, qfh[ksub], s[wt], 0, 0, 0);
            s[wt] = __builtin_amdgcn_mfma_f32_16x16x32_bf16(akh, qfl[ksub], s[wt], 0, 0, 0);
            s[wt] = __builtin_amdgcn_mfma_f32_16x16x32_bf16(akl, qfh[ksub], s[wt], 0, 0, 0);
        }
    }

    const int q_local = wid * 16 + lr;
    float sc[6][4];
    float mx = -3e38f;
    #pragma unroll
    for (int wt = 0; wt < 6; ++wt)
        #pragma unroll
        for (int j = 0; j < 4; ++j) {
            const int w = wt * 16 + lg * 4 + j;
            const bool valid = (w >= q_local) && (w <= q_local + 63) && (kt0 + w >= 0);
            sc[wt][j] = valid ? s[wt][j] * 0.125f : -3e38f;
            mx = fmaxf(mx, sc[wt][j]);
        }
    mx = fmaxf(mx, __shfl_xor(mx, 16));
    mx = fmaxf(mx, __shfl_xor(mx, 32));
    float sum = 0.f;
    #pragma unroll
    for (int wt = 0; wt < 6; ++wt)
        #pragma unroll
        for (int j = 0; j < 4; ++j) {
            sc[wt][j] = __expf(sc[wt][j] - mx);
            sum += sc[wt][j];
        }
    sum += __shfl_xor(sum, 16);
    sum += __shfl_xor(sum, 32);
    const float inv = 1.f / sum;

    #pragma unroll
    for (int wt = 0; wt < 6; ++wt) {
        ushort4 ph, pl;
        unsigned short hh, ll;
        split_val(sc[wt][0] * inv, hh, ll); ph.x = hh; pl.x = ll;
        split_val(sc[wt][1] * inv, hh, ll); ph.y = hh; pl.y = ll;
        split_val(sc[wt][2] * inv, hh, ll); ph.z = hh; pl.z = ll;
        split_val(sc[wt][3] * inv, hh, ll); ph.w = hh; pl.w = ll;
        const int col = wt * 16 + lg * 4;
        *(ushort4*)&PsH[q_local * 104 + col] = ph;
        *(ushort4*)&PsL[q_local * 104 + col] = pl;
    }

    f32x4 oa[4];
    #pragma unroll
    for (int dt = 0; dt < 4; ++dt) oa[dt] = (f32x4){0.f, 0.f, 0.f, 0.f};
    #pragma unroll
    for (int ks = 0; ks < 3; ++ks) {
        const int ka = lg * 8 + ks * 32;
        bf16frag pah = *(const bf16frag*)&PsH[(wid * 16 + lr) * 104 + ka];
        bf16frag pal = *(const bf16frag*)&PsL[(wid * 16 + lr) * 104 + ka];
        #pragma unroll
        for (int dt = 0; dt < 4; ++dt) {
            const int a = (dt * 16 + lr) * 104 + ka;
            bf16frag bvh = *(const bf16frag*)&VtH[a];
            bf16frag bvl = *(const bf16frag*)&VtL[a];
            oa[dt] = __builtin_amdgcn_mfma_f32_16x16x32_bf16(pah, bvh, oa[dt], 0, 0, 0);
            oa[dt] = __builtin_amdgcn_mfma_f32_16x16x32_bf16(pal, bvh, oa[dt], 0, 0, 0);
            oa[dt] = __builtin_amdgcn_mfma_f32_16x16x32_bf16(pah, bvl, oa[dt], 0, 0, 0);
        }
    }

    #pragma unroll
    for (int dt = 0; dt < 4; ++dt) {
        const int d = dt * 16 + lr;
        #pragma unroll
        for (int j = 0; j < 4; ++j) {
            const int t = t0 + wid * 16 + lg * 4 + j;
            unsigned short hh, ll;
            split_val(oa[dt][j], hh, ll);
            const size_t oi = (size_t)t * 512 + h * 64 + d;
            OH[oi] = hh;
            OL[oi] = ll;
        }
    }
}

extern "C" void kernel_launch(void* const* d_in, const int* in_sizes, int n_in,
                              void* d_out, int out_size, void* d_ws, size_t ws_size,
                              hipStream_t stream) {
    const float* x  = (const float*)d_in[0];
    const float* Wq = (const float*)d_in[1];
    const float* Wk = (const float*)d_in[2];
    const float* Wv = (const float*)d_in[3];
    const float* Wo = (const float*)d_in[4];
    float* out = (float*)d_out;

    const int D = 512;
    const int T = in_sizes[0] / D;        // 4096
    const size_t tdf = (size_t)T * D;
    const size_t wsz = (size_t)D * D;
    const int vtw = T + 64;
    const size_t vts = (size_t)D * vtw;

    unsigned short* qh  = (unsigned short*)d_ws;
    unsigned short* ql  = qh + tdf;
    unsigned short* kh  = ql + tdf;
    unsigned short* kl  = kh + tdf;
    unsigned short* vth = kl + tdf;
    unsigned short* vtl = vth + vts;
    unsigned short* abh = vtl + vts;
    unsigned short* abl = abh + tdf;
    unsigned short* xh  = abl + tdf;
    unsigned short* xl  = xh + tdf;
    unsigned short* wqh = xl + tdf;
    unsigned short* wql = wqh + wsz;
    unsigned short* wkh = wql + wsz;
    unsigned short* wkl = wkh + wsz;
    unsigned short* wvh = wkl + wsz;
    unsigned short* wvl = wvh + wsz;
    unsigned short* woh = wvl + wsz;
    unsigned short* wol = woh + wsz;
    // ws use ≈ 46 MB

    dim3 blk(256);
    split5<<<dim3(256, 1, 5), blk, 0, stream>>>(
        x, Wq, Wk, Wv, Wo, xh, xl, wqh, wql, wkh, wkl, wvh, wvl, woh, wol,
        (int)tdf, (int)wsz);

    // fused Q/K/V^T: 2*NQK + NVT = 768 blocks (divisible by 8 for the swizzle)
    const int NQK = 8 * (T / 128);
    const int NVT = (T / 64) * (D / 128);
    gemm_qkvt<<<dim3(2 * NQK + NVT), blk, 0, stream>>>(
        xh, xl, wqh, wql, wkh, wkl, wvh, wvl,
        qh, ql, kh, kl, vth, vtl, T, vtw);

    // attention: 8 heads x T/32 = 1024 blocks x 128 thr
    swattn5<<<dim3(8 * T / 32), dim3(128), 0, stream>>>(
        qh, ql, kh, kl, vth, vtl, abh, abl, T);

    // out-proj: fp32 to d_out, 512 blocks (1D for the swizzle)
    gemm_out<<<dim3((T / 64) * (D / 64)), blk, 0, stream>>>(
        abh, abl, woh, wol, out, T);
}